// Round 13
// baseline (276.930 us; speedup 1.0000x reference)
//
#include <hip/hip_runtime.h>

#define B_   16
#define T_   512
#define C_   1024
#define D_   4096
#define K_   128
#define WIN_ 8
#define NW_  (T_ / WIN_)   // 64
#define M_   (B_ * T_)     // 8192

typedef __attribute__((ext_vector_type(8))) short bf16x8_t;
typedef __attribute__((ext_vector_type(4))) float f32x4_t;

__device__ __forceinline__ void gload16(const void* g, void* l) {
    __builtin_amdgcn_global_load_lds(
        (const __attribute__((address_space(1))) void*)g,
        (__attribute__((address_space(3))) void*)l, 16, 0, 0);
}

__device__ __forceinline__ unsigned short f2bf(float f) {
    unsigned u = __float_as_uint(f);
    unsigned r = (u + 0x7fffu + ((u >> 16) & 1u)) >> 16;
    return (unsigned short)r;
}
__device__ __forceinline__ float bf2f(unsigned short h) {
    return __uint_as_float((unsigned)h << 16);
}

__device__ __forceinline__ unsigned f2key(float f) {
    unsigned u = __float_as_uint(f);
    return (u & 0x80000000u) ? ~u : (u | 0x80000000u);
}
__device__ __forceinline__ float key2f(unsigned k) {
    unsigned u = (k & 0x80000000u) ? (k & 0x7fffffffu) : ~k;
    return __uint_as_float(u);
}

// ---------------------------------------------------------------------------
// K0 (fused): wencbf = bf16(W_enc)  AND  benc2[d] = b_enc[d] - W_enc[d,:].b_dec
// ---------------------------------------------------------------------------
__global__ __launch_bounds__(256) void prep_cvt_wenc(
    const float* __restrict__ W_enc, const float* __restrict__ b_enc,
    const float* __restrict__ b_dec, unsigned short* __restrict__ wencbf,
    float* __restrict__ benc2)
{
    int d = blockIdx.x;
    int tid = threadIdx.x;
    float4 wv = ((const float4*)(W_enc + (size_t)d * C_))[tid];
    uint2 o;
    o.x = (unsigned)f2bf(wv.x) | ((unsigned)f2bf(wv.y) << 16);
    o.y = (unsigned)f2bf(wv.z) | ((unsigned)f2bf(wv.w) << 16);
    ((uint2*)(wencbf + (size_t)d * C_))[tid] = o;
    float4 bv = ((const float4*)b_dec)[tid];
    float s = wv.x * bv.x + wv.y * bv.y + wv.z * bv.z + wv.w * bv.w;
    __shared__ float red[256];
    red[tid] = s;
    __syncthreads();
    for (int off = 128; off > 0; off >>= 1) {
        if (tid < off) red[tid] += red[tid + off];
        __syncthreads();
    }
    if (tid == 0) benc2[d] = b_enc[d] - red[0];
}

// ---------------------------------------------------------------------------
// K1: fp32 -> bf16 (8 elems/thread) for x
// ---------------------------------------------------------------------------
__global__ void cvt_bf16(const float* __restrict__ in, unsigned short* __restrict__ out, int n8)
{
    int i = blockIdx.x * blockDim.x + threadIdx.x;
    if (i >= n8) return;
    const float4* p = (const float4*)(in + (size_t)i * 8);
    float4 a = p[0], b = p[1];
    uint4 o;
    o.x = (unsigned)f2bf(a.x) | ((unsigned)f2bf(a.y) << 16);
    o.y = (unsigned)f2bf(a.z) | ((unsigned)f2bf(a.w) << 16);
    o.z = (unsigned)f2bf(b.x) | ((unsigned)f2bf(b.y) << 16);
    o.w = (unsigned)f2bf(b.z) | ((unsigned)f2bf(b.w) << 16);
    ((uint4*)out)[i] = o;
}

// ---------------------------------------------------------------------------
// K2: transpose W_dec (C,D) -> WdTb (D,C) in bf16
// ---------------------------------------------------------------------------
__global__ void transpose_wdec(const float* __restrict__ W, unsigned short* __restrict__ WT)
{
    __shared__ float tile[32][33];
    int d0 = blockIdx.x * 32;
    int c0 = blockIdx.y * 32;
    int tx = threadIdx.x, ty = threadIdx.y;  // (32,8)
    #pragma unroll
    for (int i = 0; i < 32; i += 8)
        tile[ty + i][tx] = W[(size_t)(c0 + ty + i) * D_ + d0 + tx];
    __syncthreads();
    #pragma unroll
    for (int i = 0; i < 32; i += 8)
        WT[(size_t)(d0 + ty + i) * C_ + c0 + tx] = f2bf(tile[tx][ty + i]);
}

// ---------------------------------------------------------------------------
// K3: bf16 MFMA GEMM — round-4/7/9/10/12 proven kernel, verbatim.
// ---------------------------------------------------------------------------
__global__ __launch_bounds__(256) void mfma_gemm_dense(
    const unsigned short* __restrict__ Abf,  // x bf16 (M_, C_)
    const unsigned short* __restrict__ Bbf,  // W_enc bf16 (D_, C_)
    const float* __restrict__ benc2,
    float* __restrict__ enc,                 // (M_, D_) dense activations
    float* __restrict__ wsums)               // (B_*NW_, D_)
{
    __shared__ unsigned short lA[128 * 32];
    __shared__ unsigned short lB[128 * 32];
    __shared__ float cst[4][16][68];         // wave-private C-stage (17 KB)
    int tid = threadIdx.x;
    int lane = tid & 63;
    int wv = tid >> 6;
    int wm = wv >> 1, wn = wv & 1;

    int lid = blockIdx.y * gridDim.x + blockIdx.x;
    int sw = (lid & 7) * 256 + (lid >> 3);
    int bn = sw & 31, bm = sw >> 5;

    f32x4_t acc[4][4];
    #pragma unroll
    for (int i = 0; i < 4; i++)
        #pragma unroll
        for (int j = 0; j < 4; j++) acc[i][j] = (f32x4_t){0.f, 0.f, 0.f, 0.f};

    const unsigned short* Ab = Abf + (size_t)bm * 128 * C_;
    const unsigned short* Bb = Bbf + (size_t)bn * 128 * C_;

    int m_s[2], u_s[2];
    #pragma unroll
    for (int q = 0; q < 2; q++) {
        int p = q * 256 + tid;
        int m = p >> 2, v = p & 3;
        m_s[q] = m;
        u_s[q] = v ^ ((m >> 1) & 3);
    }

    int r = lane & 15, g = lane >> 4;
    for (int k0 = 0; k0 < C_; k0 += 32) {
        __syncthreads();
        #pragma unroll
        for (int q = 0; q < 2; q++) {
            gload16(Ab + (size_t)m_s[q] * C_ + k0 + u_s[q] * 8,
                    &lA[(q * 256 + wv * 64) * 8]);
            gload16(Bb + (size_t)m_s[q] * C_ + k0 + u_s[q] * 8,
                    &lB[(q * 256 + wv * 64) * 8]);
        }
        __syncthreads();
        bf16x8_t af[4], bfr[4];
        #pragma unroll
        for (int mi = 0; mi < 4; mi++) {
            int m = wm * 64 + mi * 16 + r;
            int u = g ^ ((m >> 1) & 3);
            af[mi] = *(const bf16x8_t*)&lA[m * 32 + u * 8];
        }
        #pragma unroll
        for (int ni = 0; ni < 4; ni++) {
            int d = wn * 64 + ni * 16 + r;
            int u = g ^ ((d >> 1) & 3);
            bfr[ni] = *(const bf16x8_t*)&lB[d * 32 + u * 8];
        }
        #pragma unroll
        for (int mi = 0; mi < 4; mi++)
            #pragma unroll
            for (int ni = 0; ni < 4; ni++)
                acc[mi][ni] = __builtin_amdgcn_mfma_f32_16x16x32_bf16(
                    af[mi], bfr[ni], acc[mi][ni], 0, 0, 0);
    }

    int b = bm >> 2;
    int t_blk = (bm & 3) * 128;
    int dbase = bn * 128 + wn * 64;
    int mbase_w = bm * 128 + wm * 64;
    int wbase = b * NW_ + (t_blk >> 3) + wm * 8;

    float bias_r[4];
    #pragma unroll
    for (int ni = 0; ni < 4; ni++) bias_r[ni] = benc2[dbase + ni * 16 + r];

    float wsv[4][4];
    #pragma unroll
    for (int mi = 0; mi < 4; mi++) {
        #pragma unroll
        for (int ni = 0; ni < 4; ni++) {
            float s = 0.f;
            #pragma unroll
            for (int q = 0; q < 4; q++) {
                float v = acc[mi][ni][q] + bias_r[ni];
                v = v > 0.f ? v : 0.f;
                cst[wv][g * 4 + q][ni * 16 + r] = v;
                s += v;
            }
            float partner = __shfl_xor(s, 16);
            wsv[mi][ni] = s + partner;
        }
        #pragma unroll
        for (int ri = 0; ri < 4; ri++) {
            int row = ri * 4 + (lane >> 4);
            int c4 = (lane & 15) * 4;
            float4 vv = *(const float4*)&cst[wv][row][c4];
            *(float4*)(enc + (size_t)(mbase_w + mi * 16 + row) * D_ + dbase + c4) = vv;
        }
    }

    if ((g & 1) == 0) {
        #pragma unroll
        for (int mi = 0; mi < 4; mi++)
            #pragma unroll
            for (int ni = 0; ni < 4; ni++)
                cst[wv][mi * 2 + (g >> 1)][ni * 16 + r] = wsv[mi][ni];
    }
    #pragma unroll
    for (int it = 0; it < 2; it++) {
        int row = lane >> 3;
        int c4 = (lane & 7) * 4 + it * 32;
        float4 vv = *(const float4*)&cst[wv][row][c4];
        *(float4*)(wsums + (size_t)(wbase + row) * D_ + dbase + c4) = vv;
    }
}

// ---------------------------------------------------------------------------
// Selection helpers (round-9/10 proven, verbatim)
// ---------------------------------------------------------------------------
__device__ __forceinline__ void find_bucket(
    const int* hist, int need, int shift, unsigned pref,
    unsigned* shp, int* shn, int tid)
{
    if (tid < 64) {
        int L = tid;
        int h0 = hist[L * 4], h1 = hist[L * 4 + 1];
        int h2 = hist[L * 4 + 2], h3 = hist[L * 4 + 3];
        int s3 = h3, s2 = h2 + s3, s1 = h1 + s2, s0 = h0 + s1;
        int T = s0, I = T;
        #pragma unroll
        for (int off = 1; off < 64; off <<= 1) {
            int t = __shfl_down(I, off);
            if (L + off < 64) I += t;
        }
        int H = I - T;   // suffix sum of buckets in higher lanes
        int S[5] = {H + s0, H + s1, H + s2, H + s3, H};
        #pragma unroll
        for (int j = 0; j < 4; j++) {
            if (S[j] >= need && S[j + 1] < need) {
                *shp = pref | ((unsigned)(L * 4 + j) << shift);
                *shn = need - S[j + 1];
            }
        }
    }
    __syncthreads();
}

__device__ __forceinline__ void radix_select(
    const unsigned* keys, int n, int need0, int npass, unsigned maxkey,
    int* hist, unsigned* shp, int* shn, int tid)
{
    if (tid == 0) { *shp = 0u; *shn = need0; }
    __syncthreads();
    for (int pass = 0; pass < npass; ++pass) {
        int shift = 24 - pass * 8;
        unsigned pref = *shp;
        int need = *shn;
        unsigned pmask = (pass == 0) ? 0u : (0xFFFFFFFFu << (shift + 8));
        hist[tid] = 0;
        __syncthreads();
        for (int i = tid; i < n; i += 256) {
            unsigned k = keys[i];
            if (k <= maxkey && (k & pmask) == pref)
                atomicAdd(&hist[(k >> shift) & 0xFF], 1);
        }
        __syncthreads();
        find_bucket(hist, need, shift, pref, shp, shn, tid);
    }
}

__device__ __forceinline__ int block_prefix_excl(int v, int* wsum, int tid)
{
    __syncthreads();                 // protect wsum reuse
    int lane = tid & 63, wv = tid >> 6;
    int x = v;
    #pragma unroll
    for (int off = 1; off < 64; off <<= 1) {
        int t = __shfl_up(x, off);
        if (lane >= off) x += t;
    }
    if (lane == 63) wsum[wv] = x;
    __syncthreads();
    int base = 0;
    #pragma unroll
    for (int w2 = 0; w2 < 3; w2++) if (w2 < wv) base += wsum[w2];
    return base + x - v;
}

// ---------------------------------------------------------------------------
// K4 (fully fused): fixup+topk (round-10 logic, bit-identical) -> in-LDS
// bitmask/sidx/popc-prefix -> mask the block's 8 enc rows in place (capturing
// selected values into LDS act) -> decode straight from LDS.
// Each window's enc/recon rows are block-exclusive: no cross-block hazards.
// ---------------------------------------------------------------------------
#define DELTA 0.15f
#define MAXCAND 320

__global__ __launch_bounds__(256) void fixup_mask_decode(
    const float* __restrict__ wsums, const float* __restrict__ x,
    const float* __restrict__ W_enc, const float* __restrict__ benc2,
    const unsigned short* __restrict__ WdTb, const float* __restrict__ b_dec,
    float* __restrict__ enc, float* __restrict__ recon)
{
    int row = blockIdx.x;             // b*NW + w
    int b = row / NW_, w = row % NW_;
    int t0g = b * T_ + w * WIN_;
    __shared__ unsigned keys[D_];     // 16 KB (mixed approx/exact keys)
    __shared__ float xs[WIN_][C_];    // 32 KB (whist in P1-pass0; act after P4)
    __shared__ int hist[256];         // 1 KB (hbits overlay in P4)
    __shared__ int wsum[4];
    __shared__ unsigned sh_prefix;
    __shared__ int sh_need;
    __shared__ int cand[MAXCAND];     // sidx+bmask_lds overlay after P3
    __shared__ unsigned ckeys[MAXCAND];  // pprefix overlay after P3
    __shared__ int sh_ncand, sh_nhi;
    unsigned short* hbits = (unsigned short*)hist;     // P4 only
    int* whist = (int*)xs;                             // [4][256], pass-0 only
    float (*act)[12] = (float(*)[12])xs;               // [128][12], after P4
    int*      sidx      = cand;                        // [128], after P3
    unsigned* bmask_lds = (unsigned*)(cand + 128);     // [128], after P3
    int*      pprefix   = (int*)ckeys;                 // [128], after P3
    int tid = threadIdx.x;

    for (int i = tid; i < D_ / 4; i += 256) {
        float4 v = ((const float4*)(wsums + (size_t)row * D_))[i];
        keys[i * 4 + 0] = f2key(v.x);
        keys[i * 4 + 1] = f2key(v.y);
        keys[i * 4 + 2] = f2key(v.z);
        keys[i * 4 + 3] = f2key(v.w);
    }
    for (int i = tid; i < 1024; i += 256) whist[i] = 0;
    if (tid == 0) { sh_ncand = 0; sh_nhi = 0; }
    __syncthreads();

    // ---- P1 pass 0: per-wave histograms ----
    {
        int* myh = whist + (tid >> 6) * 256;
        for (int i = tid; i < D_; i += 256)
            atomicAdd(&myh[keys[i] >> 24], 1);
        __syncthreads();
        hist[tid] = whist[tid] + whist[256 + tid] + whist[512 + tid] + whist[768 + tid];
        __syncthreads();
        find_bucket(hist, K_, 24, 0u, &sh_prefix, &sh_need, tid);
    }
    // ---- P1 passes 1..2 (24-bit prefix suffices) ----
    for (int pass = 1; pass < 3; ++pass) {
        int shift = 24 - pass * 8;
        unsigned pref = sh_prefix;
        int need = sh_need;
        unsigned pmask = 0xFFFFFFFFu << (shift + 8);
        hist[tid] = 0;
        __syncthreads();
        for (int i = tid; i < D_; i += 256) {
            unsigned k = keys[i];
            if ((k & pmask) == pref)
                atomicAdd(&hist[(k >> shift) & 0xFF], 1);
        }
        __syncthreads();
        find_bucket(hist, need, shift, pref, &sh_prefix, &sh_need, tid);
    }
    float kthf = key2f(sh_prefix);
    unsigned TH_HI = f2key(kthf + DELTA);
    unsigned TH_LO = f2key(kthf - DELTA);

    // ---- load xs (whist region dead now) + collect candidates ----
    for (int i = tid; i < WIN_ * C_ / 4; i += 256)
        ((float4*)xs)[i] = ((const float4*)(x + (size_t)t0g * C_))[i];
    {
        int myhi = 0;
        for (int i = tid; i < D_; i += 256) {
            unsigned k = keys[i];
            if (k > TH_HI) myhi++;
            else if (k >= TH_LO) {
                int pos = atomicAdd(&sh_ncand, 1);
                if (pos < MAXCAND) cand[pos] = i;
            }
        }
        if (myhi) atomicAdd(&sh_nhi, myhi);
    }
    __syncthreads();
    int nc = sh_ncand < MAXCAND ? sh_ncand : MAXCAND;

    // ---- P2: exact fp32 recompute (one candidate per wave) ----
    {
        int wvi = tid >> 6, ln = tid & 63;
        int c0 = ln * 4;
        for (int cb = wvi; cb < nc; cb += 4) {
            int d = cand[cb];
            const float* wrow = W_enc + (size_t)d * C_;
            float a[WIN_] = {0.f, 0.f, 0.f, 0.f, 0.f, 0.f, 0.f, 0.f};
            #pragma unroll
            for (int q = 0; q < 4; q++) {
                float4 wq = *(const float4*)(wrow + q * 256 + c0);
                #pragma unroll
                for (int j = 0; j < WIN_; j++) {
                    float4 xq = *(const float4*)(&xs[j][q * 256 + c0]);
                    a[j] = fmaf(wq.x, xq.x, a[j]);
                    a[j] = fmaf(wq.y, xq.y, a[j]);
                    a[j] = fmaf(wq.z, xq.z, a[j]);
                    a[j] = fmaf(wq.w, xq.w, a[j]);
                }
            }
            #pragma unroll
            for (int off = 1; off < 64; off <<= 1)
                #pragma unroll
                for (int j = 0; j < WIN_; j++) a[j] += __shfl_xor(a[j], off);
            if (ln == 0) {
                float bias = benc2[d], s = 0.f;
                #pragma unroll
                for (int j = 0; j < WIN_; j++) {
                    float v = a[j] + bias;
                    s += v > 0.f ? v : 0.f;
                }
                unsigned k1 = f2key(s);
                keys[d] = k1;
                ckeys[cb] = k1;
            }
        }
    }
    __syncthreads();

    // ---- P3: finish n_hi; exact select among candidates (or fallback) ----
    for (int i = tid; i < nc; i += 256)
        if (ckeys[i] > TH_HI) atomicAdd(&sh_nhi, 1);
    __syncthreads();
    int need0 = K_ - sh_nhi;
    if (need0 > 0)
        radix_select(ckeys, nc, need0, 4, TH_HI, hist, &sh_prefix, &sh_need, tid);
    else
        radix_select(keys, D_, K_, 4, 0xFFFFFFFFu, hist, &sh_prefix, &sh_need, tid);
    unsigned kth = sh_prefix;
    int need_eq = sh_need;

    // ---- P4: bitmask + ascending index list, all in LDS ----
    int base16 = tid * 16;
    unsigned mybits = 0;
    int eqcnt = 0;
    #pragma unroll
    for (int j = 0; j < 16; ++j) {
        unsigned k = keys[base16 + j];
        if (k > kth) mybits |= (1u << j);
        else if (k == kth) eqcnt++;
    }
    int rr = block_prefix_excl(eqcnt, wsum, tid);
    #pragma unroll
    for (int j = 0; j < 16; ++j) {
        unsigned k = keys[base16 + j];
        if (k == kth) { if (rr < need_eq) mybits |= (1u << j); rr++; }
    }
    hbits[tid] = (unsigned short)mybits;     // hist dead from here on
    __syncthreads();                          // also: cand/ckeys dead (post-P3)
    if (tid < 128)
        bmask_lds[tid] = (unsigned)hbits[2 * tid] | ((unsigned)hbits[2 * tid + 1] << 16);
    // popcount-exclusive-prefix over the 128 mask words (own-word read: no barrier)
    int pv = (tid < 128) ? __popc((unsigned)hbits[2 * tid] | ((unsigned)hbits[2 * tid + 1] << 16)) : 0;
    int ppref = block_prefix_excl(pv, wsum, tid);
    if (tid < 128) pprefix[tid] = ppref;
    // ascending compaction into LDS sidx
    int pos = block_prefix_excl(__popc(mybits), wsum, tid);
    #pragma unroll
    for (int j = 0; j < 16; ++j) {
        if (mybits & (1u << j)) sidx[pos++] = base16 + j;
    }
    __syncthreads();   // sidx/bmask_lds/pprefix ready; xs dead -> act overlay

    // ---- P5: mask the block's 8 enc rows in place; capture selected -> act --
    for (int jrow = 0; jrow < WIN_; jrow++) {
        float* rowp = enc + (size_t)(t0g + jrow) * D_;
        #pragma unroll
        for (int k4 = 0; k4 < 4; k4++) {
            int d4 = tid + k4 * 256;          // float4 index; d = d4*4
            int widx = d4 >> 3;
            int bit0 = (d4 & 7) * 4;
            unsigned word = bmask_lds[widx];
            unsigned nib = (word >> bit0) & 0xFu;
            float4 v = {0.f, 0.f, 0.f, 0.f};
            if (nib) {
                v = ((const float4*)rowp)[d4];
                int rk = pprefix[widx] + __popc(word & ((1u << bit0) - 1u));
                float vals[4] = {v.x, v.y, v.z, v.w};
                #pragma unroll
                for (int l = 0; l < 4; l++) {
                    if (nib & (1u << l)) { act[rk][jrow] = vals[l]; rk++; }
                    else vals[l] = 0.f;
                }
                v.x = vals[0]; v.y = vals[1]; v.z = vals[2]; v.w = vals[3];
            }
            ((float4*)rowp)[d4] = v;
        }
    }
    __syncthreads();   // act complete

    // ---- P6: decode from LDS act/sidx (no global gather) ----
    {
        float accv[WIN_][4] = {};
        int c0 = tid * 4;
        for (int i = 0; i < K_; ++i) {
            int d = sidx[i];
            ushort4 wu = *(const ushort4*)(WdTb + (size_t)d * C_ + c0);
            float4 wv = {bf2f(wu.x), bf2f(wu.y), bf2f(wu.z), bf2f(wu.w)};
            float4 a03 = *(const float4*)(&act[i][0]);
            float4 a47 = *(const float4*)(&act[i][4]);
            float aj[8] = {a03.x, a03.y, a03.z, a03.w, a47.x, a47.y, a47.z, a47.w};
            #pragma unroll
            for (int j = 0; j < WIN_; j++) {
                accv[j][0] = fmaf(aj[j], wv.x, accv[j][0]);
                accv[j][1] = fmaf(aj[j], wv.y, accv[j][1]);
                accv[j][2] = fmaf(aj[j], wv.z, accv[j][2]);
                accv[j][3] = fmaf(aj[j], wv.w, accv[j][3]);
            }
        }
        float4 bd = *(const float4*)(b_dec + c0);
        #pragma unroll
        for (int j = 0; j < WIN_; j++) {
            float4 o;
            o.x = accv[j][0] + bd.x; o.y = accv[j][1] + bd.y;
            o.z = accv[j][2] + bd.z; o.w = accv[j][3] + bd.w;
            *(float4*)(recon + (size_t)(t0g + j) * C_ + c0) = o;
        }
    }
}

// ---------------------------------------------------------------------------
extern "C" void kernel_launch(void* const* d_in, const int* in_sizes, int n_in,
                              void* d_out, int out_size, void* d_ws, size_t ws_size,
                              hipStream_t stream)
{
    const float* x     = (const float*)d_in[0];
    const float* W_enc = (const float*)d_in[1];
    const float* b_enc = (const float*)d_in[2];
    const float* W_dec = (const float*)d_in[3];
    const float* b_dec = (const float*)d_in[4];

    float* out   = (float*)d_out;
    float* recon = out;                        // M_*C_ floats
    float* enc   = out + (size_t)M_ * C_;      // M_*D_ floats (dense -> masked)

    // scratch inside recon region (dead before fused kernel writes recon)
    unsigned short* xbf   = (unsigned short*)recon;                       // 16.8 MB
    float*          wsums = (float*)((char*)recon + (size_t)M_ * C_ * 2); // 16.8 MB

    // persistent scratch in d_ws
    char* ws = (char*)d_ws;
    unsigned short* WdTb    = (unsigned short*)ws;                          // 8.4 MB (bf16)
    float*          benc2   = (float*)(ws + (size_t)D_ * C_ * 2);           // 16 KB
    unsigned short* wencbf  = (unsigned short*)((char*)benc2 + D_ * 4);     // 8.4 MB

    prep_cvt_wenc<<<D_, 256, 0, stream>>>(W_enc, b_enc, b_dec, wencbf, benc2);
    cvt_bf16<<<(M_ * C_ / 8 + 255) / 256, 256, 0, stream>>>(x, xbf, M_ * C_ / 8);
    transpose_wdec<<<dim3(D_ / 32, C_ / 32), dim3(32, 8), 0, stream>>>(W_dec, WdTb);
    mfma_gemm_dense<<<dim3(32, 64), 256, 0, stream>>>(xbf, wencbf, benc2, enc, wsums);
    fixup_mask_decode<<<B_ * NW_, 256, 0, stream>>>(
        wsums, x, W_enc, benc2, WdTb, b_dec, enc, recon);
}

// Round 14
// 263.621 us; speedup vs baseline: 1.0505x; 1.0505x over previous
//
#include <hip/hip_runtime.h>

#define B_   16
#define T_   512
#define C_   1024
#define D_   4096
#define K_   128
#define WIN_ 8
#define NW_  (T_ / WIN_)   // 64
#define M_   (B_ * T_)     // 8192

typedef __attribute__((ext_vector_type(8))) short bf16x8_t;
typedef __attribute__((ext_vector_type(4))) float f32x4_t;

__device__ __forceinline__ void gload16(const void* g, void* l) {
    __builtin_amdgcn_global_load_lds(
        (const __attribute__((address_space(1))) void*)g,
        (__attribute__((address_space(3))) void*)l, 16, 0, 0);
}

__device__ __forceinline__ unsigned short f2bf(float f) {
    unsigned u = __float_as_uint(f);
    unsigned r = (u + 0x7fffu + ((u >> 16) & 1u)) >> 16;
    return (unsigned short)r;
}
__device__ __forceinline__ float bf2f(unsigned short h) {
    return __uint_as_float((unsigned)h << 16);
}

__device__ __forceinline__ unsigned f2key(float f) {
    unsigned u = __float_as_uint(f);
    return (u & 0x80000000u) ? ~u : (u | 0x80000000u);
}
__device__ __forceinline__ float key2f(unsigned k) {
    unsigned u = (k & 0x80000000u) ? (k & 0x7fffffffu) : ~k;
    return __uint_as_float(u);
}

// ---------------------------------------------------------------------------
// K0 (fused): wencbf = bf16(W_enc)  AND  benc2[d] = b_enc[d] - W_enc[d,:].b_dec
// ---------------------------------------------------------------------------
__global__ __launch_bounds__(256) void prep_cvt_wenc(
    const float* __restrict__ W_enc, const float* __restrict__ b_enc,
    const float* __restrict__ b_dec, unsigned short* __restrict__ wencbf,
    float* __restrict__ benc2)
{
    int d = blockIdx.x;
    int tid = threadIdx.x;
    float4 wv = ((const float4*)(W_enc + (size_t)d * C_))[tid];
    uint2 o;
    o.x = (unsigned)f2bf(wv.x) | ((unsigned)f2bf(wv.y) << 16);
    o.y = (unsigned)f2bf(wv.z) | ((unsigned)f2bf(wv.w) << 16);
    ((uint2*)(wencbf + (size_t)d * C_))[tid] = o;
    float4 bv = ((const float4*)b_dec)[tid];
    float s = wv.x * bv.x + wv.y * bv.y + wv.z * bv.z + wv.w * bv.w;
    __shared__ float red[256];
    red[tid] = s;
    __syncthreads();
    for (int off = 128; off > 0; off >>= 1) {
        if (tid < off) red[tid] += red[tid + off];
        __syncthreads();
    }
    if (tid == 0) benc2[d] = b_enc[d] - red[0];
}

// ---------------------------------------------------------------------------
// K1: fp32 -> bf16 (8 elems/thread) for x
// ---------------------------------------------------------------------------
__global__ void cvt_bf16(const float* __restrict__ in, unsigned short* __restrict__ out, int n8)
{
    int i = blockIdx.x * blockDim.x + threadIdx.x;
    if (i >= n8) return;
    const float4* p = (const float4*)(in + (size_t)i * 8);
    float4 a = p[0], b = p[1];
    uint4 o;
    o.x = (unsigned)f2bf(a.x) | ((unsigned)f2bf(a.y) << 16);
    o.y = (unsigned)f2bf(a.z) | ((unsigned)f2bf(a.w) << 16);
    o.z = (unsigned)f2bf(b.x) | ((unsigned)f2bf(b.y) << 16);
    o.w = (unsigned)f2bf(b.z) | ((unsigned)f2bf(b.w) << 16);
    ((uint4*)out)[i] = o;
}

// ---------------------------------------------------------------------------
// K2: transpose W_dec (C,D) -> WdTb (D,C) in bf16
// ---------------------------------------------------------------------------
__global__ void transpose_wdec(const float* __restrict__ W, unsigned short* __restrict__ WT)
{
    __shared__ float tile[32][33];
    int d0 = blockIdx.x * 32;
    int c0 = blockIdx.y * 32;
    int tx = threadIdx.x, ty = threadIdx.y;  // (32,8)
    #pragma unroll
    for (int i = 0; i < 32; i += 8)
        tile[ty + i][tx] = W[(size_t)(c0 + ty + i) * D_ + d0 + tx];
    __syncthreads();
    #pragma unroll
    for (int i = 0; i < 32; i += 8)
        WT[(size_t)(d0 + ty + i) * C_ + c0 + tx] = f2bf(tile[tx][ty + i]);
}

// ---------------------------------------------------------------------------
// K3: bf16 MFMA GEMM — round-4/7/9/10/12/13 proven kernel, verbatim.
// ---------------------------------------------------------------------------
__global__ __launch_bounds__(256) void mfma_gemm_dense(
    const unsigned short* __restrict__ Abf,  // x bf16 (M_, C_)
    const unsigned short* __restrict__ Bbf,  // W_enc bf16 (D_, C_)
    const float* __restrict__ benc2,
    float* __restrict__ enc,                 // (M_, D_) dense activations
    float* __restrict__ wsums)               // (B_*NW_, D_)
{
    __shared__ unsigned short lA[128 * 32];
    __shared__ unsigned short lB[128 * 32];
    __shared__ float cst[4][16][68];         // wave-private C-stage (17 KB)
    int tid = threadIdx.x;
    int lane = tid & 63;
    int wv = tid >> 6;
    int wm = wv >> 1, wn = wv & 1;

    int lid = blockIdx.y * gridDim.x + blockIdx.x;
    int sw = (lid & 7) * 256 + (lid >> 3);
    int bn = sw & 31, bm = sw >> 5;

    f32x4_t acc[4][4];
    #pragma unroll
    for (int i = 0; i < 4; i++)
        #pragma unroll
        for (int j = 0; j < 4; j++) acc[i][j] = (f32x4_t){0.f, 0.f, 0.f, 0.f};

    const unsigned short* Ab = Abf + (size_t)bm * 128 * C_;
    const unsigned short* Bb = Bbf + (size_t)bn * 128 * C_;

    int m_s[2], u_s[2];
    #pragma unroll
    for (int q = 0; q < 2; q++) {
        int p = q * 256 + tid;
        int m = p >> 2, v = p & 3;
        m_s[q] = m;
        u_s[q] = v ^ ((m >> 1) & 3);
    }

    int r = lane & 15, g = lane >> 4;
    for (int k0 = 0; k0 < C_; k0 += 32) {
        __syncthreads();
        #pragma unroll
        for (int q = 0; q < 2; q++) {
            gload16(Ab + (size_t)m_s[q] * C_ + k0 + u_s[q] * 8,
                    &lA[(q * 256 + wv * 64) * 8]);
            gload16(Bb + (size_t)m_s[q] * C_ + k0 + u_s[q] * 8,
                    &lB[(q * 256 + wv * 64) * 8]);
        }
        __syncthreads();
        bf16x8_t af[4], bfr[4];
        #pragma unroll
        for (int mi = 0; mi < 4; mi++) {
            int m = wm * 64 + mi * 16 + r;
            int u = g ^ ((m >> 1) & 3);
            af[mi] = *(const bf16x8_t*)&lA[m * 32 + u * 8];
        }
        #pragma unroll
        for (int ni = 0; ni < 4; ni++) {
            int d = wn * 64 + ni * 16 + r;
            int u = g ^ ((d >> 1) & 3);
            bfr[ni] = *(const bf16x8_t*)&lB[d * 32 + u * 8];
        }
        #pragma unroll
        for (int mi = 0; mi < 4; mi++)
            #pragma unroll
            for (int ni = 0; ni < 4; ni++)
                acc[mi][ni] = __builtin_amdgcn_mfma_f32_16x16x32_bf16(
                    af[mi], bfr[ni], acc[mi][ni], 0, 0, 0);
    }

    int b = bm >> 2;
    int t_blk = (bm & 3) * 128;
    int dbase = bn * 128 + wn * 64;
    int mbase_w = bm * 128 + wm * 64;
    int wbase = b * NW_ + (t_blk >> 3) + wm * 8;

    float bias_r[4];
    #pragma unroll
    for (int ni = 0; ni < 4; ni++) bias_r[ni] = benc2[dbase + ni * 16 + r];

    float wsv[4][4];
    #pragma unroll
    for (int mi = 0; mi < 4; mi++) {
        #pragma unroll
        for (int ni = 0; ni < 4; ni++) {
            float s = 0.f;
            #pragma unroll
            for (int q = 0; q < 4; q++) {
                float v = acc[mi][ni][q] + bias_r[ni];
                v = v > 0.f ? v : 0.f;
                cst[wv][g * 4 + q][ni * 16 + r] = v;
                s += v;
            }
            float partner = __shfl_xor(s, 16);
            wsv[mi][ni] = s + partner;
        }
        #pragma unroll
        for (int ri = 0; ri < 4; ri++) {
            int row = ri * 4 + (lane >> 4);
            int c4 = (lane & 15) * 4;
            float4 vv = *(const float4*)&cst[wv][row][c4];
            *(float4*)(enc + (size_t)(mbase_w + mi * 16 + row) * D_ + dbase + c4) = vv;
        }
    }

    if ((g & 1) == 0) {
        #pragma unroll
        for (int mi = 0; mi < 4; mi++)
            #pragma unroll
            for (int ni = 0; ni < 4; ni++)
                cst[wv][mi * 2 + (g >> 1)][ni * 16 + r] = wsv[mi][ni];
    }
    #pragma unroll
    for (int it = 0; it < 2; it++) {
        int row = lane >> 3;
        int c4 = (lane & 7) * 4 + it * 32;
        float4 vv = *(const float4*)&cst[wv][row][c4];
        *(float4*)(wsums + (size_t)(wbase + row) * D_ + dbase + c4) = vv;
    }
}

// ---------------------------------------------------------------------------
// Selection helpers (proven, verbatim)
// ---------------------------------------------------------------------------
__device__ __forceinline__ void find_bucket(
    const int* hist, int need, int shift, unsigned pref,
    unsigned* shp, int* shn, int tid)
{
    if (tid < 64) {
        int L = tid;
        int h0 = hist[L * 4], h1 = hist[L * 4 + 1];
        int h2 = hist[L * 4 + 2], h3 = hist[L * 4 + 3];
        int s3 = h3, s2 = h2 + s3, s1 = h1 + s2, s0 = h0 + s1;
        int T = s0, I = T;
        #pragma unroll
        for (int off = 1; off < 64; off <<= 1) {
            int t = __shfl_down(I, off);
            if (L + off < 64) I += t;
        }
        int H = I - T;   // suffix sum of buckets in higher lanes
        int S[5] = {H + s0, H + s1, H + s2, H + s3, H};
        #pragma unroll
        for (int j = 0; j < 4; j++) {
            if (S[j] >= need && S[j + 1] < need) {
                *shp = pref | ((unsigned)(L * 4 + j) << shift);
                *shn = need - S[j + 1];
            }
        }
    }
    __syncthreads();
}

__device__ __forceinline__ void radix_select(
    const unsigned* keys, int n, int need0, int npass, unsigned maxkey,
    int* hist, unsigned* shp, int* shn, int tid)
{
    if (tid == 0) { *shp = 0u; *shn = need0; }
    __syncthreads();
    for (int pass = 0; pass < npass; ++pass) {
        int shift = 24 - pass * 8;
        unsigned pref = *shp;
        int need = *shn;
        unsigned pmask = (pass == 0) ? 0u : (0xFFFFFFFFu << (shift + 8));
        hist[tid] = 0;
        __syncthreads();
        for (int i = tid; i < n; i += 256) {
            unsigned k = keys[i];
            if (k <= maxkey && (k & pmask) == pref)
                atomicAdd(&hist[(k >> shift) & 0xFF], 1);
        }
        __syncthreads();
        find_bucket(hist, need, shift, pref, shp, shn, tid);
    }
}

__device__ __forceinline__ int block_prefix_excl(int v, int* wsum, int tid)
{
    __syncthreads();                 // protect wsum reuse
    int lane = tid & 63, wv = tid >> 6;
    int x = v;
    #pragma unroll
    for (int off = 1; off < 64; off <<= 1) {
        int t = __shfl_up(x, off);
        if (lane >= off) x += t;
    }
    if (lane == 63) wsum[wv] = x;
    __syncthreads();
    int base = 0;
    #pragma unroll
    for (int w2 = 0; w2 < 3; w2++) if (w2 < wv) base += wsum[w2];
    return base + x - v;
}

// ---------------------------------------------------------------------------
// K4 (fully fused): round-13 kernel; ONLY change = P6 decode loop 4x unrolled
// with all four WdTb row loads issued before the FMA groups (4 loads in
// flight instead of 1). Accumulation order preserved exactly (i,i+1,i+2,i+3).
// ---------------------------------------------------------------------------
#define DELTA 0.15f
#define MAXCAND 320

__global__ __launch_bounds__(256) void fixup_mask_decode(
    const float* __restrict__ wsums, const float* __restrict__ x,
    const float* __restrict__ W_enc, const float* __restrict__ benc2,
    const unsigned short* __restrict__ WdTb, const float* __restrict__ b_dec,
    float* __restrict__ enc, float* __restrict__ recon)
{
    int row = blockIdx.x;             // b*NW + w
    int b = row / NW_, w = row % NW_;
    int t0g = b * T_ + w * WIN_;
    __shared__ unsigned keys[D_];     // 16 KB (mixed approx/exact keys)
    __shared__ float xs[WIN_][C_];    // 32 KB (whist in P1-pass0; act after P4)
    __shared__ int hist[256];         // 1 KB (hbits overlay in P4)
    __shared__ int wsum[4];
    __shared__ unsigned sh_prefix;
    __shared__ int sh_need;
    __shared__ int cand[MAXCAND];     // sidx+bmask_lds overlay after P3
    __shared__ unsigned ckeys[MAXCAND];  // pprefix overlay after P3
    __shared__ int sh_ncand, sh_nhi;
    unsigned short* hbits = (unsigned short*)hist;     // P4 only
    int* whist = (int*)xs;                             // [4][256], pass-0 only
    float (*act)[12] = (float(*)[12])xs;               // [128][12], after P4
    int*      sidx      = cand;                        // [128], after P3
    unsigned* bmask_lds = (unsigned*)(cand + 128);     // [128], after P3
    int*      pprefix   = (int*)ckeys;                 // [128], after P3
    int tid = threadIdx.x;

    for (int i = tid; i < D_ / 4; i += 256) {
        float4 v = ((const float4*)(wsums + (size_t)row * D_))[i];
        keys[i * 4 + 0] = f2key(v.x);
        keys[i * 4 + 1] = f2key(v.y);
        keys[i * 4 + 2] = f2key(v.z);
        keys[i * 4 + 3] = f2key(v.w);
    }
    for (int i = tid; i < 1024; i += 256) whist[i] = 0;
    if (tid == 0) { sh_ncand = 0; sh_nhi = 0; }
    __syncthreads();

    // ---- P1 pass 0: per-wave histograms ----
    {
        int* myh = whist + (tid >> 6) * 256;
        for (int i = tid; i < D_; i += 256)
            atomicAdd(&myh[keys[i] >> 24], 1);
        __syncthreads();
        hist[tid] = whist[tid] + whist[256 + tid] + whist[512 + tid] + whist[768 + tid];
        __syncthreads();
        find_bucket(hist, K_, 24, 0u, &sh_prefix, &sh_need, tid);
    }
    // ---- P1 passes 1..2 (24-bit prefix suffices) ----
    for (int pass = 1; pass < 3; ++pass) {
        int shift = 24 - pass * 8;
        unsigned pref = sh_prefix;
        int need = sh_need;
        unsigned pmask = 0xFFFFFFFFu << (shift + 8);
        hist[tid] = 0;
        __syncthreads();
        for (int i = tid; i < D_; i += 256) {
            unsigned k = keys[i];
            if ((k & pmask) == pref)
                atomicAdd(&hist[(k >> shift) & 0xFF], 1);
        }
        __syncthreads();
        find_bucket(hist, need, shift, pref, &sh_prefix, &sh_need, tid);
    }
    float kthf = key2f(sh_prefix);
    unsigned TH_HI = f2key(kthf + DELTA);
    unsigned TH_LO = f2key(kthf - DELTA);

    // ---- load xs (whist region dead now) + collect candidates ----
    for (int i = tid; i < WIN_ * C_ / 4; i += 256)
        ((float4*)xs)[i] = ((const float4*)(x + (size_t)t0g * C_))[i];
    {
        int myhi = 0;
        for (int i = tid; i < D_; i += 256) {
            unsigned k = keys[i];
            if (k > TH_HI) myhi++;
            else if (k >= TH_LO) {
                int pos = atomicAdd(&sh_ncand, 1);
                if (pos < MAXCAND) cand[pos] = i;
            }
        }
        if (myhi) atomicAdd(&sh_nhi, myhi);
    }
    __syncthreads();
    int nc = sh_ncand < MAXCAND ? sh_ncand : MAXCAND;

    // ---- P2: exact fp32 recompute (one candidate per wave) ----
    {
        int wvi = tid >> 6, ln = tid & 63;
        int c0 = ln * 4;
        for (int cb = wvi; cb < nc; cb += 4) {
            int d = cand[cb];
            const float* wrow = W_enc + (size_t)d * C_;
            float a[WIN_] = {0.f, 0.f, 0.f, 0.f, 0.f, 0.f, 0.f, 0.f};
            #pragma unroll
            for (int q = 0; q < 4; q++) {
                float4 wq = *(const float4*)(wrow + q * 256 + c0);
                #pragma unroll
                for (int j = 0; j < WIN_; j++) {
                    float4 xq = *(const float4*)(&xs[j][q * 256 + c0]);
                    a[j] = fmaf(wq.x, xq.x, a[j]);
                    a[j] = fmaf(wq.y, xq.y, a[j]);
                    a[j] = fmaf(wq.z, xq.z, a[j]);
                    a[j] = fmaf(wq.w, xq.w, a[j]);
                }
            }
            #pragma unroll
            for (int off = 1; off < 64; off <<= 1)
                #pragma unroll
                for (int j = 0; j < WIN_; j++) a[j] += __shfl_xor(a[j], off);
            if (ln == 0) {
                float bias = benc2[d], s = 0.f;
                #pragma unroll
                for (int j = 0; j < WIN_; j++) {
                    float v = a[j] + bias;
                    s += v > 0.f ? v : 0.f;
                }
                unsigned k1 = f2key(s);
                keys[d] = k1;
                ckeys[cb] = k1;
            }
        }
    }
    __syncthreads();

    // ---- P3: finish n_hi; exact select among candidates (or fallback) ----
    for (int i = tid; i < nc; i += 256)
        if (ckeys[i] > TH_HI) atomicAdd(&sh_nhi, 1);
    __syncthreads();
    int need0 = K_ - sh_nhi;
    if (need0 > 0)
        radix_select(ckeys, nc, need0, 4, TH_HI, hist, &sh_prefix, &sh_need, tid);
    else
        radix_select(keys, D_, K_, 4, 0xFFFFFFFFu, hist, &sh_prefix, &sh_need, tid);
    unsigned kth = sh_prefix;
    int need_eq = sh_need;

    // ---- P4: bitmask + ascending index list, all in LDS ----
    int base16 = tid * 16;
    unsigned mybits = 0;
    int eqcnt = 0;
    #pragma unroll
    for (int j = 0; j < 16; ++j) {
        unsigned k = keys[base16 + j];
        if (k > kth) mybits |= (1u << j);
        else if (k == kth) eqcnt++;
    }
    int rr = block_prefix_excl(eqcnt, wsum, tid);
    #pragma unroll
    for (int j = 0; j < 16; ++j) {
        unsigned k = keys[base16 + j];
        if (k == kth) { if (rr < need_eq) mybits |= (1u << j); rr++; }
    }
    hbits[tid] = (unsigned short)mybits;     // hist dead from here on
    __syncthreads();                          // also: cand/ckeys dead (post-P3)
    if (tid < 128)
        bmask_lds[tid] = (unsigned)hbits[2 * tid] | ((unsigned)hbits[2 * tid + 1] << 16);
    int pv = (tid < 128) ? __popc((unsigned)hbits[2 * tid] | ((unsigned)hbits[2 * tid + 1] << 16)) : 0;
    int ppref = block_prefix_excl(pv, wsum, tid);
    if (tid < 128) pprefix[tid] = ppref;
    int pos = block_prefix_excl(__popc(mybits), wsum, tid);
    #pragma unroll
    for (int j = 0; j < 16; ++j) {
        if (mybits & (1u << j)) sidx[pos++] = base16 + j;
    }
    __syncthreads();   // sidx/bmask_lds/pprefix ready; xs dead -> act overlay

    // ---- P5: mask the block's 8 enc rows in place; capture selected -> act --
    for (int jrow = 0; jrow < WIN_; jrow++) {
        float* rowp = enc + (size_t)(t0g + jrow) * D_;
        #pragma unroll
        for (int k4 = 0; k4 < 4; k4++) {
            int d4 = tid + k4 * 256;          // float4 index; d = d4*4
            int widx = d4 >> 3;
            int bit0 = (d4 & 7) * 4;
            unsigned word = bmask_lds[widx];
            unsigned nib = (word >> bit0) & 0xFu;
            float4 v = {0.f, 0.f, 0.f, 0.f};
            if (nib) {
                v = ((const float4*)rowp)[d4];
                int rk = pprefix[widx] + __popc(word & ((1u << bit0) - 1u));
                float vals[4] = {v.x, v.y, v.z, v.w};
                #pragma unroll
                for (int l = 0; l < 4; l++) {
                    if (nib & (1u << l)) { act[rk][jrow] = vals[l]; rk++; }
                    else vals[l] = 0.f;
                }
                v.x = vals[0]; v.y = vals[1]; v.z = vals[2]; v.w = vals[3];
            }
            ((float4*)rowp)[d4] = v;
        }
    }
    __syncthreads();   // act complete

    // ---- P6: decode from LDS act/sidx — 4x unrolled, 4 row-loads in flight --
    {
        float accv[WIN_][4] = {};
        int c0 = tid * 4;
        for (int i = 0; i < K_; i += 4) {
            int d0v = sidx[i + 0], d1v = sidx[i + 1];
            int d2v = sidx[i + 2], d3v = sidx[i + 3];
            ushort4 wu0 = *(const ushort4*)(WdTb + (size_t)d0v * C_ + c0);
            ushort4 wu1 = *(const ushort4*)(WdTb + (size_t)d1v * C_ + c0);
            ushort4 wu2 = *(const ushort4*)(WdTb + (size_t)d2v * C_ + c0);
            ushort4 wu3 = *(const ushort4*)(WdTb + (size_t)d3v * C_ + c0);
            #pragma unroll
            for (int u = 0; u < 4; u++) {
                ushort4 wu = (u == 0) ? wu0 : (u == 1) ? wu1 : (u == 2) ? wu2 : wu3;
                float4 wv = {bf2f(wu.x), bf2f(wu.y), bf2f(wu.z), bf2f(wu.w)};
                const float* ar = act[i + u];
                #pragma unroll
                for (int j = 0; j < WIN_; j++) {
                    float aj = ar[j];
                    accv[j][0] = fmaf(aj, wv.x, accv[j][0]);
                    accv[j][1] = fmaf(aj, wv.y, accv[j][1]);
                    accv[j][2] = fmaf(aj, wv.z, accv[j][2]);
                    accv[j][3] = fmaf(aj, wv.w, accv[j][3]);
                }
            }
        }
        float4 bd = *(const float4*)(b_dec + c0);
        #pragma unroll
        for (int j = 0; j < WIN_; j++) {
            float4 o;
            o.x = accv[j][0] + bd.x; o.y = accv[j][1] + bd.y;
            o.z = accv[j][2] + bd.z; o.w = accv[j][3] + bd.w;
            *(float4*)(recon + (size_t)(t0g + j) * C_ + c0) = o;
        }
    }
}

// ---------------------------------------------------------------------------
extern "C" void kernel_launch(void* const* d_in, const int* in_sizes, int n_in,
                              void* d_out, int out_size, void* d_ws, size_t ws_size,
                              hipStream_t stream)
{
    const float* x     = (const float*)d_in[0];
    const float* W_enc = (const float*)d_in[1];
    const float* b_enc = (const float*)d_in[2];
    const float* W_dec = (const float*)d_in[3];
    const float* b_dec = (const float*)d_in[4];

    float* out   = (float*)d_out;
    float* recon = out;                        // M_*C_ floats
    float* enc   = out + (size_t)M_ * C_;      // M_*D_ floats (dense -> masked)

    // scratch inside recon region (dead before fused kernel writes recon)
    unsigned short* xbf   = (unsigned short*)recon;                       // 16.8 MB
    float*          wsums = (float*)((char*)recon + (size_t)M_ * C_ * 2); // 16.8 MB

    // persistent scratch in d_ws
    char* ws = (char*)d_ws;
    unsigned short* WdTb    = (unsigned short*)ws;                          // 8.4 MB (bf16)
    float*          benc2   = (float*)(ws + (size_t)D_ * C_ * 2);           // 16 KB
    unsigned short* wencbf  = (unsigned short*)((char*)benc2 + D_ * 4);     // 8.4 MB

    prep_cvt_wenc<<<D_, 256, 0, stream>>>(W_enc, b_enc, b_dec, wencbf, benc2);
    cvt_bf16<<<(M_ * C_ / 8 + 255) / 256, 256, 0, stream>>>(x, xbf, M_ * C_ / 8);
    transpose_wdec<<<dim3(D_ / 32, C_ / 32), dim3(32, 8), 0, stream>>>(W_dec, WdTb);
    mfma_gemm_dense<<<dim3(32, 64), 256, 0, stream>>>(xbf, wencbf, benc2, enc, wsums);
    fixup_mask_decode<<<B_ * NW_, 256, 0, stream>>>(
        wsums, x, W_enc, benc2, WdTb, b_dec, enc, recon);
}

// Round 15
// 247.677 us; speedup vs baseline: 1.1181x; 1.0644x over previous
//
#include <hip/hip_runtime.h>

#define B_   16
#define T_   512
#define C_   1024
#define D_   4096
#define K_   128
#define WIN_ 8
#define NW_  (T_ / WIN_)   // 64
#define M_   (B_ * T_)     // 8192

typedef __attribute__((ext_vector_type(8))) short bf16x8_t;
typedef __attribute__((ext_vector_type(4))) float f32x4_t;

__device__ __forceinline__ void gload16(const void* g, void* l) {
    __builtin_amdgcn_global_load_lds(
        (const __attribute__((address_space(1))) void*)g,
        (__attribute__((address_space(3))) void*)l, 16, 0, 0);
}

__device__ __forceinline__ unsigned short f2bf(float f) {
    unsigned u = __float_as_uint(f);
    unsigned r = (u + 0x7fffu + ((u >> 16) & 1u)) >> 16;
    return (unsigned short)r;
}
__device__ __forceinline__ float bf2f(unsigned short h) {
    return __uint_as_float((unsigned)h << 16);
}

__device__ __forceinline__ unsigned f2key(float f) {
    unsigned u = __float_as_uint(f);
    return (u & 0x80000000u) ? ~u : (u | 0x80000000u);
}
__device__ __forceinline__ float key2f(unsigned k) {
    unsigned u = (k & 0x80000000u) ? (k & 0x7fffffffu) : ~k;
    return __uint_as_float(u);
}

// ---------------------------------------------------------------------------
// K0 (fused): wencbf = bf16(W_enc)  AND  benc2[d] = b_enc[d] - W_enc[d,:].b_dec
// ---------------------------------------------------------------------------
__global__ __launch_bounds__(256) void prep_cvt_wenc(
    const float* __restrict__ W_enc, const float* __restrict__ b_enc,
    const float* __restrict__ b_dec, unsigned short* __restrict__ wencbf,
    float* __restrict__ benc2)
{
    int d = blockIdx.x;
    int tid = threadIdx.x;
    float4 wv = ((const float4*)(W_enc + (size_t)d * C_))[tid];
    uint2 o;
    o.x = (unsigned)f2bf(wv.x) | ((unsigned)f2bf(wv.y) << 16);
    o.y = (unsigned)f2bf(wv.z) | ((unsigned)f2bf(wv.w) << 16);
    ((uint2*)(wencbf + (size_t)d * C_))[tid] = o;
    float4 bv = ((const float4*)b_dec)[tid];
    float s = wv.x * bv.x + wv.y * bv.y + wv.z * bv.z + wv.w * bv.w;
    __shared__ float red[256];
    red[tid] = s;
    __syncthreads();
    for (int off = 128; off > 0; off >>= 1) {
        if (tid < off) red[tid] += red[tid + off];
        __syncthreads();
    }
    if (tid == 0) benc2[d] = b_enc[d] - red[0];
}

// ---------------------------------------------------------------------------
// K1: fp32 -> bf16 (8 elems/thread) for x
// ---------------------------------------------------------------------------
__global__ void cvt_bf16(const float* __restrict__ in, unsigned short* __restrict__ out, int n8)
{
    int i = blockIdx.x * blockDim.x + threadIdx.x;
    if (i >= n8) return;
    const float4* p = (const float4*)(in + (size_t)i * 8);
    float4 a = p[0], b = p[1];
    uint4 o;
    o.x = (unsigned)f2bf(a.x) | ((unsigned)f2bf(a.y) << 16);
    o.y = (unsigned)f2bf(a.z) | ((unsigned)f2bf(a.w) << 16);
    o.z = (unsigned)f2bf(b.x) | ((unsigned)f2bf(b.y) << 16);
    o.w = (unsigned)f2bf(b.z) | ((unsigned)f2bf(b.w) << 16);
    ((uint4*)out)[i] = o;
}

// ---------------------------------------------------------------------------
// K2: transpose W_dec (C,D) -> WdTb (D,C) in bf16
// ---------------------------------------------------------------------------
__global__ void transpose_wdec(const float* __restrict__ W, unsigned short* __restrict__ WT)
{
    __shared__ float tile[32][33];
    int d0 = blockIdx.x * 32;
    int c0 = blockIdx.y * 32;
    int tx = threadIdx.x, ty = threadIdx.y;  // (32,8)
    #pragma unroll
    for (int i = 0; i < 32; i += 8)
        tile[ty + i][tx] = W[(size_t)(c0 + ty + i) * D_ + d0 + tx];
    __syncthreads();
    #pragma unroll
    for (int i = 0; i < 32; i += 8)
        WT[(size_t)(d0 + ty + i) * C_ + c0 + tx] = f2bf(tile[tx][ty + i]);
}

// ---------------------------------------------------------------------------
// K3: bf16 MFMA GEMM — proven K-loop; epilogue now stores WINDOW SUMS ONLY
// (dense activations recomputed bit-exactly in K4's MFMA phase).
// ---------------------------------------------------------------------------
__global__ __launch_bounds__(256) void mfma_gemm_ws(
    const unsigned short* __restrict__ Abf,  // x bf16 (M_, C_)
    const unsigned short* __restrict__ Bbf,  // W_enc bf16 (D_, C_)
    const float* __restrict__ benc2,
    float* __restrict__ wsums)               // (B_*NW_, D_)
{
    __shared__ unsigned short lA[128 * 32];
    __shared__ unsigned short lB[128 * 32];
    __shared__ float cst[4][8][68];          // wave-private ws stage (8.7 KB)
    int tid = threadIdx.x;
    int lane = tid & 63;
    int wv = tid >> 6;
    int wm = wv >> 1, wn = wv & 1;

    int lid = blockIdx.y * gridDim.x + blockIdx.x;
    int sw = (lid & 7) * 256 + (lid >> 3);
    int bn = sw & 31, bm = sw >> 5;

    f32x4_t acc[4][4];
    #pragma unroll
    for (int i = 0; i < 4; i++)
        #pragma unroll
        for (int j = 0; j < 4; j++) acc[i][j] = (f32x4_t){0.f, 0.f, 0.f, 0.f};

    const unsigned short* Ab = Abf + (size_t)bm * 128 * C_;
    const unsigned short* Bb = Bbf + (size_t)bn * 128 * C_;

    int m_s[2], u_s[2];
    #pragma unroll
    for (int q = 0; q < 2; q++) {
        int p = q * 256 + tid;
        int m = p >> 2, v = p & 3;
        m_s[q] = m;
        u_s[q] = v ^ ((m >> 1) & 3);
    }

    int r = lane & 15, g = lane >> 4;
    for (int k0 = 0; k0 < C_; k0 += 32) {
        __syncthreads();
        #pragma unroll
        for (int q = 0; q < 2; q++) {
            gload16(Ab + (size_t)m_s[q] * C_ + k0 + u_s[q] * 8,
                    &lA[(q * 256 + wv * 64) * 8]);
            gload16(Bb + (size_t)m_s[q] * C_ + k0 + u_s[q] * 8,
                    &lB[(q * 256 + wv * 64) * 8]);
        }
        __syncthreads();
        bf16x8_t af[4], bfr[4];
        #pragma unroll
        for (int mi = 0; mi < 4; mi++) {
            int m = wm * 64 + mi * 16 + r;
            int u = g ^ ((m >> 1) & 3);
            af[mi] = *(const bf16x8_t*)&lA[m * 32 + u * 8];
        }
        #pragma unroll
        for (int ni = 0; ni < 4; ni++) {
            int d = wn * 64 + ni * 16 + r;
            int u = g ^ ((d >> 1) & 3);
            bfr[ni] = *(const bf16x8_t*)&lB[d * 32 + u * 8];
        }
        #pragma unroll
        for (int mi = 0; mi < 4; mi++)
            #pragma unroll
            for (int ni = 0; ni < 4; ni++)
                acc[mi][ni] = __builtin_amdgcn_mfma_f32_16x16x32_bf16(
                    af[mi], bfr[ni], acc[mi][ni], 0, 0, 0);
    }

    int b = bm >> 2;
    int t_blk = (bm & 3) * 128;
    int dbase = bn * 128 + wn * 64;
    int wbase = b * NW_ + (t_blk >> 3) + wm * 8;

    float bias_r[4];
    #pragma unroll
    for (int ni = 0; ni < 4; ni++) bias_r[ni] = benc2[dbase + ni * 16 + r];

    #pragma unroll
    for (int mi = 0; mi < 4; mi++) {
        #pragma unroll
        for (int ni = 0; ni < 4; ni++) {
            float s = 0.f;
            #pragma unroll
            for (int q = 0; q < 4; q++) {
                float v = acc[mi][ni][q] + bias_r[ni];
                v = v > 0.f ? v : 0.f;
                s += v;
            }
            float partner = __shfl_xor(s, 16);   // pair lane-groups (0,1),(2,3)
            float wsv = s + partner;
            if ((g & 1) == 0)
                cst[wv][mi * 2 + (g >> 1)][ni * 16 + r] = wsv;
        }
    }
    // same-wave LDS write->read; compiler inserts lgkmcnt
    #pragma unroll
    for (int it = 0; it < 2; it++) {
        int rowq = lane >> 3;
        int c4 = (lane & 7) * 4 + it * 32;
        float4 vv = *(const float4*)&cst[wv][rowq][c4];
        *(float4*)(wsums + (size_t)(wbase + rowq) * D_ + dbase + c4) = vv;
    }
}

// ---------------------------------------------------------------------------
// Selection helpers (proven, verbatim)
// ---------------------------------------------------------------------------
__device__ __forceinline__ void find_bucket(
    const int* hist, int need, int shift, unsigned pref,
    unsigned* shp, int* shn, int tid)
{
    if (tid < 64) {
        int L = tid;
        int h0 = hist[L * 4], h1 = hist[L * 4 + 1];
        int h2 = hist[L * 4 + 2], h3 = hist[L * 4 + 3];
        int s3 = h3, s2 = h2 + s3, s1 = h1 + s2, s0 = h0 + s1;
        int T = s0, I = T;
        #pragma unroll
        for (int off = 1; off < 64; off <<= 1) {
            int t = __shfl_down(I, off);
            if (L + off < 64) I += t;
        }
        int H = I - T;   // suffix sum of buckets in higher lanes
        int S[5] = {H + s0, H + s1, H + s2, H + s3, H};
        #pragma unroll
        for (int j = 0; j < 4; j++) {
            if (S[j] >= need && S[j + 1] < need) {
                *shp = pref | ((unsigned)(L * 4 + j) << shift);
                *shn = need - S[j + 1];
            }
        }
    }
    __syncthreads();
}

__device__ __forceinline__ void radix_select(
    const unsigned* keys, int n, int need0, int npass, unsigned maxkey,
    int* hist, unsigned* shp, int* shn, int tid)
{
    if (tid == 0) { *shp = 0u; *shn = need0; }
    __syncthreads();
    for (int pass = 0; pass < npass; ++pass) {
        int shift = 24 - pass * 8;
        unsigned pref = *shp;
        int need = *shn;
        unsigned pmask = (pass == 0) ? 0u : (0xFFFFFFFFu << (shift + 8));
        hist[tid] = 0;
        __syncthreads();
        for (int i = tid; i < n; i += 256) {
            unsigned k = keys[i];
            if (k <= maxkey && (k & pmask) == pref)
                atomicAdd(&hist[(k >> shift) & 0xFF], 1);
        }
        __syncthreads();
        find_bucket(hist, need, shift, pref, shp, shn, tid);
    }
}

__device__ __forceinline__ int block_prefix_excl(int v, int* wsum, int tid)
{
    __syncthreads();                 // protect wsum reuse
    int lane = tid & 63, wv = tid >> 6;
    int x = v;
    #pragma unroll
    for (int off = 1; off < 64; off <<= 1) {
        int t = __shfl_up(x, off);
        if (lane >= off) x += t;
    }
    if (lane == 63) wsum[wv] = x;
    __syncthreads();
    int base = 0;
    #pragma unroll
    for (int w2 = 0; w2 < 3; w2++) if (w2 < wv) base += wsum[w2];
    return base + x - v;
}

// ---------------------------------------------------------------------------
// K4 (fully fused): selection (round-14 logic, bit-identical) -> MFMA
// recompute of the 128 selected activations (bit-exact vs the old dense GEMM:
// same instruction, same k-order, same bf16 inputs, same bias/relu order) ->
// pure-write enc (zeros + act, no global read) -> decode.
// ---------------------------------------------------------------------------
#define DELTA 0.15f
#define MAXCAND 320

__global__ __launch_bounds__(256) void fixup_mask_decode(
    const float* __restrict__ wsums, const float* __restrict__ x,
    const float* __restrict__ W_enc, const float* __restrict__ benc2,
    const unsigned short* __restrict__ wencbf,
    const unsigned short* __restrict__ WdTb, const float* __restrict__ b_dec,
    float* __restrict__ enc, float* __restrict__ recon)
{
    int row = blockIdx.x;             // b*NW + w
    int b = row / NW_, w = row % NW_;
    int t0g = b * T_ + w * WIN_;
    __shared__ unsigned keys[D_];     // 16 KB (act[128][12] overlay after P4)
    __shared__ float xs[WIN_][C_];    // 32 KB (whist overlay during P1)
    __shared__ int hist[256];         // 1 KB (hbits overlay in P4)
    __shared__ int wsum[4];
    __shared__ unsigned sh_prefix;
    __shared__ int sh_need;
    __shared__ int cand[MAXCAND];     // sidx+bmask_lds overlay after P3
    __shared__ unsigned ckeys[MAXCAND];  // pprefix overlay after P3
    __shared__ int sh_ncand, sh_nhi;
    unsigned short* hbits = (unsigned short*)hist;     // P4 only
    int* whist = (int*)xs;                             // [4][256], pass-0 only
    float (*act)[12] = (float(*)[12])keys;             // [128][12], after P4
    int*      sidx      = cand;                        // [128], after P3
    unsigned* bmask_lds = (unsigned*)(cand + 128);     // [128], after P3
    int*      pprefix   = (int*)ckeys;                 // [128], after P3
    int tid = threadIdx.x;

    for (int i = tid; i < D_ / 4; i += 256) {
        float4 v = ((const float4*)(wsums + (size_t)row * D_))[i];
        keys[i * 4 + 0] = f2key(v.x);
        keys[i * 4 + 1] = f2key(v.y);
        keys[i * 4 + 2] = f2key(v.z);
        keys[i * 4 + 3] = f2key(v.w);
    }
    for (int i = tid; i < 1024; i += 256) whist[i] = 0;
    if (tid == 0) { sh_ncand = 0; sh_nhi = 0; }
    __syncthreads();

    // ---- P1 pass 0: per-wave histograms ----
    {
        int* myh = whist + (tid >> 6) * 256;
        for (int i = tid; i < D_; i += 256)
            atomicAdd(&myh[keys[i] >> 24], 1);
        __syncthreads();
        hist[tid] = whist[tid] + whist[256 + tid] + whist[512 + tid] + whist[768 + tid];
        __syncthreads();
        find_bucket(hist, K_, 24, 0u, &sh_prefix, &sh_need, tid);
    }
    // ---- P1 passes 1..2 (24-bit prefix suffices) ----
    for (int pass = 1; pass < 3; ++pass) {
        int shift = 24 - pass * 8;
        unsigned pref = sh_prefix;
        int need = sh_need;
        unsigned pmask = 0xFFFFFFFFu << (shift + 8);
        hist[tid] = 0;
        __syncthreads();
        for (int i = tid; i < D_; i += 256) {
            unsigned k = keys[i];
            if ((k & pmask) == pref)
                atomicAdd(&hist[(k >> shift) & 0xFF], 1);
        }
        __syncthreads();
        find_bucket(hist, need, shift, pref, &sh_prefix, &sh_need, tid);
    }
    float kthf = key2f(sh_prefix);
    unsigned TH_HI = f2key(kthf + DELTA);
    unsigned TH_LO = f2key(kthf - DELTA);

    // ---- load xs (whist region dead now) + collect candidates ----
    for (int i = tid; i < WIN_ * C_ / 4; i += 256)
        ((float4*)xs)[i] = ((const float4*)(x + (size_t)t0g * C_))[i];
    {
        int myhi = 0;
        for (int i = tid; i < D_; i += 256) {
            unsigned k = keys[i];
            if (k > TH_HI) myhi++;
            else if (k >= TH_LO) {
                int pos = atomicAdd(&sh_ncand, 1);
                if (pos < MAXCAND) cand[pos] = i;
            }
        }
        if (myhi) atomicAdd(&sh_nhi, myhi);
    }
    __syncthreads();
    int nc = sh_ncand < MAXCAND ? sh_ncand : MAXCAND;

    // ---- P2: exact fp32 recompute (one candidate per wave) ----
    {
        int wvi = tid >> 6, ln = tid & 63;
        int c0 = ln * 4;
        for (int cb = wvi; cb < nc; cb += 4) {
            int d = cand[cb];
            const float* wrow = W_enc + (size_t)d * C_;
            float a[WIN_] = {0.f, 0.f, 0.f, 0.f, 0.f, 0.f, 0.f, 0.f};
            #pragma unroll
            for (int q = 0; q < 4; q++) {
                float4 wq = *(const float4*)(wrow + q * 256 + c0);
                #pragma unroll
                for (int j = 0; j < WIN_; j++) {
                    float4 xq = *(const float4*)(&xs[j][q * 256 + c0]);
                    a[j] = fmaf(wq.x, xq.x, a[j]);
                    a[j] = fmaf(wq.y, xq.y, a[j]);
                    a[j] = fmaf(wq.z, xq.z, a[j]);
                    a[j] = fmaf(wq.w, xq.w, a[j]);
                }
            }
            #pragma unroll
            for (int off = 1; off < 64; off <<= 1)
                #pragma unroll
                for (int j = 0; j < WIN_; j++) a[j] += __shfl_xor(a[j], off);
            if (ln == 0) {
                float bias = benc2[d], s = 0.f;
                #pragma unroll
                for (int j = 0; j < WIN_; j++) {
                    float v = a[j] + bias;
                    s += v > 0.f ? v : 0.f;
                }
                unsigned k1 = f2key(s);
                keys[d] = k1;
                ckeys[cb] = k1;
            }
        }
    }
    __syncthreads();

    // ---- P3: finish n_hi; exact select among candidates (or fallback) ----
    for (int i = tid; i < nc; i += 256)
        if (ckeys[i] > TH_HI) atomicAdd(&sh_nhi, 1);
    __syncthreads();
    int need0 = K_ - sh_nhi;
    if (need0 > 0)
        radix_select(ckeys, nc, need0, 4, TH_HI, hist, &sh_prefix, &sh_need, tid);
    else
        radix_select(keys, D_, K_, 4, 0xFFFFFFFFu, hist, &sh_prefix, &sh_need, tid);
    unsigned kth = sh_prefix;
    int need_eq = sh_need;

    // ---- P4: bitmask + ascending index list, all in LDS ----
    int base16 = tid * 16;
    unsigned mybits = 0;
    int eqcnt = 0;
    #pragma unroll
    for (int j = 0; j < 16; ++j) {
        unsigned k = keys[base16 + j];
        if (k > kth) mybits |= (1u << j);
        else if (k == kth) eqcnt++;
    }
    int rr = block_prefix_excl(eqcnt, wsum, tid);
    #pragma unroll
    for (int j = 0; j < 16; ++j) {
        unsigned k = keys[base16 + j];
        if (k == kth) { if (rr < need_eq) mybits |= (1u << j); rr++; }
    }
    hbits[tid] = (unsigned short)mybits;     // hist dead from here on
    __syncthreads();
    if (tid < 128)
        bmask_lds[tid] = (unsigned)hbits[2 * tid] | ((unsigned)hbits[2 * tid + 1] << 16);
    int pv = (tid < 128) ? __popc((unsigned)hbits[2 * tid] | ((unsigned)hbits[2 * tid + 1] << 16)) : 0;
    int ppref = block_prefix_excl(pv, wsum, tid);
    if (tid < 128) pprefix[tid] = ppref;
    int pos = block_prefix_excl(__popc(mybits), wsum, tid);
    #pragma unroll
    for (int j = 0; j < 16; ++j) {
        if (mybits & (1u << j)) sidx[pos++] = base16 + j;
    }
    __syncthreads();   // sidx/bmask_lds/pprefix ready; keys dead -> act overlay

    // ---- P5a: MFMA recompute of the 128 selected activations ----
    // A = gathered W_enc bf16 rows (1st operand -> output rows = selected),
    // B = x window bf16 (2nd operand -> output cols = t). Same instruction,
    // k-order, inputs, bias/relu order as the former dense GEMM => bit-exact.
    {
        int lane = tid & 63;
        int r = lane & 15, g = lane >> 4;
        int wvq = tid >> 6;              // wave handles tiles wvq*2, wvq*2+1
        int tsrc = (r < WIN_) ? r : 0;
        int rowA0 = sidx[(wvq * 2 + 0) * 16 + r];
        int rowA1 = sidx[(wvq * 2 + 1) * 16 + r];
        const unsigned short* pa0 = wencbf + (size_t)rowA0 * C_;
        const unsigned short* pa1 = wencbf + (size_t)rowA1 * C_;
        f32x4_t acca0 = (f32x4_t){0.f, 0.f, 0.f, 0.f};
        f32x4_t acca1 = (f32x4_t){0.f, 0.f, 0.f, 0.f};
        for (int k0 = 0; k0 < C_; k0 += 32) {
            bf16x8_t bfrag;
            #pragma unroll
            for (int j = 0; j < 8; j++)
                bfrag[j] = (short)f2bf(xs[tsrc][k0 + g * 8 + j]);
            bf16x8_t a0 = *(const bf16x8_t*)(pa0 + k0 + g * 8);
            bf16x8_t a1 = *(const bf16x8_t*)(pa1 + k0 + g * 8);
            acca0 = __builtin_amdgcn_mfma_f32_16x16x32_bf16(a0, bfrag, acca0, 0, 0, 0);
            acca1 = __builtin_amdgcn_mfma_f32_16x16x32_bf16(a1, bfrag, acca1, 0, 0, 0);
        }
        if (r < WIN_) {
            #pragma unroll
            for (int q = 0; q < 4; q++) {
                int s0 = (wvq * 2 + 0) * 16 + g * 4 + q;
                float v0 = acca0[q] + benc2[sidx[s0]];
                act[s0][r] = v0 > 0.f ? v0 : 0.f;
                int s1 = (wvq * 2 + 1) * 16 + g * 4 + q;
                float v1 = acca1[q] + benc2[sidx[s1]];
                act[s1][r] = v1 > 0.f ? v1 : 0.f;
            }
        }
    }
    __syncthreads();   // act complete

    // ---- P5b: write enc = zeros + selected values (pure write, no read) ----
    for (int jrow = 0; jrow < WIN_; jrow++) {
        float* rowp = enc + (size_t)(t0g + jrow) * D_;
        #pragma unroll
        for (int k4 = 0; k4 < 4; k4++) {
            int d4 = tid + k4 * 256;          // float4 index; d = d4*4
            int widx = d4 >> 3;
            int bit0 = (d4 & 7) * 4;
            unsigned word = bmask_lds[widx];
            unsigned nib = (word >> bit0) & 0xFu;
            float4 v = {0.f, 0.f, 0.f, 0.f};
            if (nib) {
                int rk = pprefix[widx] + __popc(word & ((1u << bit0) - 1u));
                #pragma unroll
                for (int l = 0; l < 4; l++) {
                    if (nib & (1u << l)) { ((float*)&v)[l] = act[rk][jrow]; rk++; }
                }
            }
            ((float4*)rowp)[d4] = v;
        }
    }

    // ---- P6: decode from LDS act/sidx — 8 row-loads in flight ----
    {
        float accv[WIN_][4] = {};
        int c0 = tid * 4;
        for (int i = 0; i < K_; i += 8) {
            ushort4 wu[8];
            #pragma unroll
            for (int u = 0; u < 8; u++)
                wu[u] = *(const ushort4*)(WdTb + (size_t)sidx[i + u] * C_ + c0);
            #pragma unroll
            for (int u = 0; u < 8; u++) {
                float4 wv = {bf2f(wu[u].x), bf2f(wu[u].y), bf2f(wu[u].z), bf2f(wu[u].w)};
                const float* ar = act[i + u];
                #pragma unroll
                for (int j = 0; j < WIN_; j++) {
                    float aj = ar[j];
                    accv[j][0] = fmaf(aj, wv.x, accv[j][0]);
                    accv[j][1] = fmaf(aj, wv.y, accv[j][1]);
                    accv[j][2] = fmaf(aj, wv.z, accv[j][2]);
                    accv[j][3] = fmaf(aj, wv.w, accv[j][3]);
                }
            }
        }
        float4 bd = *(const float4*)(b_dec + c0);
        #pragma unroll
        for (int j = 0; j < WIN_; j++) {
            float4 o;
            o.x = accv[j][0] + bd.x; o.y = accv[j][1] + bd.y;
            o.z = accv[j][2] + bd.z; o.w = accv[j][3] + bd.w;
            *(float4*)(recon + (size_t)(t0g + j) * C_ + c0) = o;
        }
    }
}

// ---------------------------------------------------------------------------
extern "C" void kernel_launch(void* const* d_in, const int* in_sizes, int n_in,
                              void* d_out, int out_size, void* d_ws, size_t ws_size,
                              hipStream_t stream)
{
    const float* x     = (const float*)d_in[0];
    const float* W_enc = (const float*)d_in[1];
    const float* b_enc = (const float*)d_in[2];
    const float* W_dec = (const float*)d_in[3];
    const float* b_dec = (const float*)d_in[4];

    float* out   = (float*)d_out;
    float* recon = out;                        // M_*C_ floats
    float* enc   = out + (size_t)M_ * C_;      // M_*D_ floats (written once)

    // scratch inside recon region:
    //   xbf read only by the GEMM kernel (stream-ordered before the fused
    //   kernel); wsums read only at fused-kernel block start (proven pattern)
    unsigned short* xbf   = (unsigned short*)recon;                       // 16.8 MB
    float*          wsums = (float*)((char*)recon + (size_t)M_ * C_ * 2); // 16.8 MB

    // persistent scratch in d_ws
    char* ws = (char*)d_ws;
    unsigned short* WdTb    = (unsigned short*)ws;                          // 8.4 MB (bf16)
    float*          benc2   = (float*)(ws + (size_t)D_ * C_ * 2);           // 16 KB
    unsigned short* wencbf  = (unsigned short*)((char*)benc2 + D_ * 4);     // 8.4 MB

    prep_cvt_wenc<<<D_, 256, 0, stream>>>(W_enc, b_enc, b_dec, wencbf, benc2);
    cvt_bf16<<<(M_ * C_ / 8 + 255) / 256, 256, 0, stream>>>(x, xbf, M_ * C_ / 8);
    transpose_wdec<<<dim3(D_ / 32, C_ / 32), dim3(32, 8), 0, stream>>>(W_dec, WdTb);
    mfma_gemm_ws<<<dim3(32, 64), 256, 0, stream>>>(xbf, wencbf, benc2, wsums);
    fixup_mask_decode<<<B_ * NW_, 256, 0, stream>>>(
        wsums, x, W_enc, benc2, wencbf, WdTb, b_dec, enc, recon);
}

// Round 16
// 245.667 us; speedup vs baseline: 1.1273x; 1.0082x over previous
//
#include <hip/hip_runtime.h>

#define B_   16
#define T_   512
#define C_   1024
#define D_   4096
#define K_   128
#define WIN_ 8
#define NW_  (T_ / WIN_)   // 64
#define M_   (B_ * T_)     // 8192

typedef __attribute__((ext_vector_type(8))) short bf16x8_t;
typedef __attribute__((ext_vector_type(4))) float f32x4_t;

__device__ __forceinline__ void gload16(const void* g, void* l) {
    __builtin_amdgcn_global_load_lds(
        (const __attribute__((address_space(1))) void*)g,
        (__attribute__((address_space(3))) void*)l, 16, 0, 0);
}

__device__ __forceinline__ unsigned short f2bf(float f) {
    unsigned u = __float_as_uint(f);
    unsigned r = (u + 0x7fffu + ((u >> 16) & 1u)) >> 16;
    return (unsigned short)r;
}
__device__ __forceinline__ float bf2f(unsigned short h) {
    return __uint_as_float((unsigned)h << 16);
}

__device__ __forceinline__ unsigned f2key(float f) {
    unsigned u = __float_as_uint(f);
    return (u & 0x80000000u) ? ~u : (u | 0x80000000u);
}
__device__ __forceinline__ float key2f(unsigned k) {
    unsigned u = (k & 0x80000000u) ? (k & 0x7fffffffu) : ~k;
    return __uint_as_float(u);
}

// ---------------------------------------------------------------------------
// K0 (fused): wencbf = bf16(W_enc)  AND  benc2[d] = b_enc[d] - W_enc[d,:].b_dec
// ---------------------------------------------------------------------------
__global__ __launch_bounds__(256) void prep_cvt_wenc(
    const float* __restrict__ W_enc, const float* __restrict__ b_enc,
    const float* __restrict__ b_dec, unsigned short* __restrict__ wencbf,
    float* __restrict__ benc2)
{
    int d = blockIdx.x;
    int tid = threadIdx.x;
    float4 wv = ((const float4*)(W_enc + (size_t)d * C_))[tid];
    uint2 o;
    o.x = (unsigned)f2bf(wv.x) | ((unsigned)f2bf(wv.y) << 16);
    o.y = (unsigned)f2bf(wv.z) | ((unsigned)f2bf(wv.w) << 16);
    ((uint2*)(wencbf + (size_t)d * C_))[tid] = o;
    float4 bv = ((const float4*)b_dec)[tid];
    float s = wv.x * bv.x + wv.y * bv.y + wv.z * bv.z + wv.w * bv.w;
    __shared__ float red[256];
    red[tid] = s;
    __syncthreads();
    for (int off = 128; off > 0; off >>= 1) {
        if (tid < off) red[tid] += red[tid + off];
        __syncthreads();
    }
    if (tid == 0) benc2[d] = b_enc[d] - red[0];
}

// ---------------------------------------------------------------------------
// K1: fp32 -> bf16 (8 elems/thread) for x
// ---------------------------------------------------------------------------
__global__ void cvt_bf16(const float* __restrict__ in, unsigned short* __restrict__ out, int n8)
{
    int i = blockIdx.x * blockDim.x + threadIdx.x;
    if (i >= n8) return;
    const float4* p = (const float4*)(in + (size_t)i * 8);
    float4 a = p[0], b = p[1];
    uint4 o;
    o.x = (unsigned)f2bf(a.x) | ((unsigned)f2bf(a.y) << 16);
    o.y = (unsigned)f2bf(a.z) | ((unsigned)f2bf(a.w) << 16);
    o.z = (unsigned)f2bf(b.x) | ((unsigned)f2bf(b.y) << 16);
    o.w = (unsigned)f2bf(b.z) | ((unsigned)f2bf(b.w) << 16);
    ((uint4*)out)[i] = o;
}

// ---------------------------------------------------------------------------
// K2: transpose W_dec (C,D) -> WdTb (D,C) in bf16
// ---------------------------------------------------------------------------
__global__ void transpose_wdec(const float* __restrict__ W, unsigned short* __restrict__ WT)
{
    __shared__ float tile[32][33];
    int d0 = blockIdx.x * 32;
    int c0 = blockIdx.y * 32;
    int tx = threadIdx.x, ty = threadIdx.y;  // (32,8)
    #pragma unroll
    for (int i = 0; i < 32; i += 8)
        tile[ty + i][tx] = W[(size_t)(c0 + ty + i) * D_ + d0 + tx];
    __syncthreads();
    #pragma unroll
    for (int i = 0; i < 32; i += 8)
        WT[(size_t)(d0 + ty + i) * C_ + c0 + tx] = f2bf(tile[tx][ty + i]);
}

// ---------------------------------------------------------------------------
// K3: bf16 MFMA GEMM — proven K-loop; ws-only epilogue (round-15, verbatim).
// ---------------------------------------------------------------------------
__global__ __launch_bounds__(256) void mfma_gemm_ws(
    const unsigned short* __restrict__ Abf,  // x bf16 (M_, C_)
    const unsigned short* __restrict__ Bbf,  // W_enc bf16 (D_, C_)
    const float* __restrict__ benc2,
    float* __restrict__ wsums)               // (B_*NW_, D_)
{
    __shared__ unsigned short lA[128 * 32];
    __shared__ unsigned short lB[128 * 32];
    __shared__ float cst[4][8][68];          // wave-private ws stage (8.7 KB)
    int tid = threadIdx.x;
    int lane = tid & 63;
    int wv = tid >> 6;
    int wm = wv >> 1, wn = wv & 1;

    int lid = blockIdx.y * gridDim.x + blockIdx.x;
    int sw = (lid & 7) * 256 + (lid >> 3);
    int bn = sw & 31, bm = sw >> 5;

    f32x4_t acc[4][4];
    #pragma unroll
    for (int i = 0; i < 4; i++)
        #pragma unroll
        for (int j = 0; j < 4; j++) acc[i][j] = (f32x4_t){0.f, 0.f, 0.f, 0.f};

    const unsigned short* Ab = Abf + (size_t)bm * 128 * C_;
    const unsigned short* Bb = Bbf + (size_t)bn * 128 * C_;

    int m_s[2], u_s[2];
    #pragma unroll
    for (int q = 0; q < 2; q++) {
        int p = q * 256 + tid;
        int m = p >> 2, v = p & 3;
        m_s[q] = m;
        u_s[q] = v ^ ((m >> 1) & 3);
    }

    int r = lane & 15, g = lane >> 4;
    for (int k0 = 0; k0 < C_; k0 += 32) {
        __syncthreads();
        #pragma unroll
        for (int q = 0; q < 2; q++) {
            gload16(Ab + (size_t)m_s[q] * C_ + k0 + u_s[q] * 8,
                    &lA[(q * 256 + wv * 64) * 8]);
            gload16(Bb + (size_t)m_s[q] * C_ + k0 + u_s[q] * 8,
                    &lB[(q * 256 + wv * 64) * 8]);
        }
        __syncthreads();
        bf16x8_t af[4], bfr[4];
        #pragma unroll
        for (int mi = 0; mi < 4; mi++) {
            int m = wm * 64 + mi * 16 + r;
            int u = g ^ ((m >> 1) & 3);
            af[mi] = *(const bf16x8_t*)&lA[m * 32 + u * 8];
        }
        #pragma unroll
        for (int ni = 0; ni < 4; ni++) {
            int d = wn * 64 + ni * 16 + r;
            int u = g ^ ((d >> 1) & 3);
            bfr[ni] = *(const bf16x8_t*)&lB[d * 32 + u * 8];
        }
        #pragma unroll
        for (int mi = 0; mi < 4; mi++)
            #pragma unroll
            for (int ni = 0; ni < 4; ni++)
                acc[mi][ni] = __builtin_amdgcn_mfma_f32_16x16x32_bf16(
                    af[mi], bfr[ni], acc[mi][ni], 0, 0, 0);
    }

    int b = bm >> 2;
    int t_blk = (bm & 3) * 128;
    int dbase = bn * 128 + wn * 64;
    int wbase = b * NW_ + (t_blk >> 3) + wm * 8;

    float bias_r[4];
    #pragma unroll
    for (int ni = 0; ni < 4; ni++) bias_r[ni] = benc2[dbase + ni * 16 + r];

    #pragma unroll
    for (int mi = 0; mi < 4; mi++) {
        #pragma unroll
        for (int ni = 0; ni < 4; ni++) {
            float s = 0.f;
            #pragma unroll
            for (int q = 0; q < 4; q++) {
                float v = acc[mi][ni][q] + bias_r[ni];
                v = v > 0.f ? v : 0.f;
                s += v;
            }
            float partner = __shfl_xor(s, 16);   // pair lane-groups (0,1),(2,3)
            float wsv = s + partner;
            if ((g & 1) == 0)
                cst[wv][mi * 2 + (g >> 1)][ni * 16 + r] = wsv;
        }
    }
    #pragma unroll
    for (int it = 0; it < 2; it++) {
        int rowq = lane >> 3;
        int c4 = (lane & 7) * 4 + it * 32;
        float4 vv = *(const float4*)&cst[wv][rowq][c4];
        *(float4*)(wsums + (size_t)(wbase + rowq) * D_ + dbase + c4) = vv;
    }
}

// ---------------------------------------------------------------------------
// Selection helpers (proven, verbatim)
// ---------------------------------------------------------------------------
__device__ __forceinline__ void find_bucket(
    const int* hist, int need, int shift, unsigned pref,
    unsigned* shp, int* shn, int tid)
{
    if (tid < 64) {
        int L = tid;
        int h0 = hist[L * 4], h1 = hist[L * 4 + 1];
        int h2 = hist[L * 4 + 2], h3 = hist[L * 4 + 3];
        int s3 = h3, s2 = h2 + s3, s1 = h1 + s2, s0 = h0 + s1;
        int T = s0, I = T;
        #pragma unroll
        for (int off = 1; off < 64; off <<= 1) {
            int t = __shfl_down(I, off);
            if (L + off < 64) I += t;
        }
        int H = I - T;   // suffix sum of buckets in higher lanes
        int S[5] = {H + s0, H + s1, H + s2, H + s3, H};
        #pragma unroll
        for (int j = 0; j < 4; j++) {
            if (S[j] >= need && S[j + 1] < need) {
                *shp = pref | ((unsigned)(L * 4 + j) << shift);
                *shn = need - S[j + 1];
            }
        }
    }
    __syncthreads();
}

__device__ __forceinline__ void radix_select(
    const unsigned* keys, int n, int need0, int npass, unsigned maxkey,
    int* hist, unsigned* shp, int* shn, int tid)
{
    if (tid == 0) { *shp = 0u; *shn = need0; }
    __syncthreads();
    for (int pass = 0; pass < npass; ++pass) {
        int shift = 24 - pass * 8;
        unsigned pref = *shp;
        int need = *shn;
        unsigned pmask = (pass == 0) ? 0u : (0xFFFFFFFFu << (shift + 8));
        hist[tid] = 0;
        __syncthreads();
        for (int i = tid; i < n; i += 256) {
            unsigned k = keys[i];
            if (k <= maxkey && (k & pmask) == pref)
                atomicAdd(&hist[(k >> shift) & 0xFF], 1);
        }
        __syncthreads();
        find_bucket(hist, need, shift, pref, shp, shn, tid);
    }
}

__device__ __forceinline__ int block_prefix_excl(int v, int* wsum, int tid)
{
    __syncthreads();                 // protect wsum reuse
    int lane = tid & 63, wv = tid >> 6;
    int x = v;
    #pragma unroll
    for (int off = 1; off < 64; off <<= 1) {
        int t = __shfl_up(x, off);
        if (lane >= off) x += t;
    }
    if (lane == 63) wsum[wv] = x;
    __syncthreads();
    int base = 0;
    #pragma unroll
    for (int w2 = 0; w2 < 3; w2++) if (w2 < wv) base += wsum[w2];
    return base + x - v;
}

// ---------------------------------------------------------------------------
// K4 (fully fused): round-15 logic; changes = P2 cross-candidate load
// prefetch and P6 double-buffered row prefetch (both bit-exact: identical
// FMA sequences, only load timing moved).
// ---------------------------------------------------------------------------
#define DELTA 0.15f
#define MAXCAND 320

__global__ __launch_bounds__(256) void fixup_mask_decode(
    const float* __restrict__ wsums, const float* __restrict__ x,
    const float* __restrict__ W_enc, const float* __restrict__ benc2,
    const unsigned short* __restrict__ wencbf,
    const unsigned short* __restrict__ WdTb, const float* __restrict__ b_dec,
    float* __restrict__ enc, float* __restrict__ recon)
{
    int row = blockIdx.x;             // b*NW + w
    int b = row / NW_, w = row % NW_;
    int t0g = b * T_ + w * WIN_;
    __shared__ unsigned keys[D_];     // 16 KB (act[128][12] overlay after P4)
    __shared__ float xs[WIN_][C_];    // 32 KB (whist overlay during P1)
    __shared__ int hist[256];         // 1 KB (hbits overlay in P4)
    __shared__ int wsum[4];
    __shared__ unsigned sh_prefix;
    __shared__ int sh_need;
    __shared__ int cand[MAXCAND];     // sidx+bmask_lds overlay after P3
    __shared__ unsigned ckeys[MAXCAND];  // pprefix overlay after P3
    __shared__ int sh_ncand, sh_nhi;
    unsigned short* hbits = (unsigned short*)hist;     // P4 only
    int* whist = (int*)xs;                             // [4][256], pass-0 only
    float (*act)[12] = (float(*)[12])keys;             // [128][12], after P4
    int*      sidx      = cand;                        // [128], after P3
    unsigned* bmask_lds = (unsigned*)(cand + 128);     // [128], after P3
    int*      pprefix   = (int*)ckeys;                 // [128], after P3
    int tid = threadIdx.x;

    for (int i = tid; i < D_ / 4; i += 256) {
        float4 v = ((const float4*)(wsums + (size_t)row * D_))[i];
        keys[i * 4 + 0] = f2key(v.x);
        keys[i * 4 + 1] = f2key(v.y);
        keys[i * 4 + 2] = f2key(v.z);
        keys[i * 4 + 3] = f2key(v.w);
    }
    for (int i = tid; i < 1024; i += 256) whist[i] = 0;
    if (tid == 0) { sh_ncand = 0; sh_nhi = 0; }
    __syncthreads();

    // ---- P1 pass 0: per-wave histograms ----
    {
        int* myh = whist + (tid >> 6) * 256;
        for (int i = tid; i < D_; i += 256)
            atomicAdd(&myh[keys[i] >> 24], 1);
        __syncthreads();
        hist[tid] = whist[tid] + whist[256 + tid] + whist[512 + tid] + whist[768 + tid];
        __syncthreads();
        find_bucket(hist, K_, 24, 0u, &sh_prefix, &sh_need, tid);
    }
    // ---- P1 passes 1..2 (24-bit prefix suffices) ----
    for (int pass = 1; pass < 3; ++pass) {
        int shift = 24 - pass * 8;
        unsigned pref = sh_prefix;
        int need = sh_need;
        unsigned pmask = 0xFFFFFFFFu << (shift + 8);
        hist[tid] = 0;
        __syncthreads();
        for (int i = tid; i < D_; i += 256) {
            unsigned k = keys[i];
            if ((k & pmask) == pref)
                atomicAdd(&hist[(k >> shift) & 0xFF], 1);
        }
        __syncthreads();
        find_bucket(hist, need, shift, pref, &sh_prefix, &sh_need, tid);
    }
    float kthf = key2f(sh_prefix);
    unsigned TH_HI = f2key(kthf + DELTA);
    unsigned TH_LO = f2key(kthf - DELTA);

    // ---- load xs (whist region dead now) + collect candidates ----
    for (int i = tid; i < WIN_ * C_ / 4; i += 256)
        ((float4*)xs)[i] = ((const float4*)(x + (size_t)t0g * C_))[i];
    {
        int myhi = 0;
        for (int i = tid; i < D_; i += 256) {
            unsigned k = keys[i];
            if (k > TH_HI) myhi++;
            else if (k >= TH_LO) {
                int pos = atomicAdd(&sh_ncand, 1);
                if (pos < MAXCAND) cand[pos] = i;
            }
        }
        if (myhi) atomicAdd(&sh_nhi, myhi);
    }
    __syncthreads();
    int nc = sh_ncand < MAXCAND ? sh_ncand : MAXCAND;

    // ---- P2: exact fp32 recompute, cross-candidate load prefetch ----
    // (FMA order per candidate identical to round 15 -> bit-exact keys)
    {
        int wvi = tid >> 6, ln = tid & 63;
        int c0 = ln * 4;
        float4 pw0, pw1, pw2, pw3;
        if (wvi < nc) {
            const float* wr = W_enc + (size_t)cand[wvi] * C_;
            pw0 = *(const float4*)(wr + 0 * 256 + c0);
            pw1 = *(const float4*)(wr + 1 * 256 + c0);
            pw2 = *(const float4*)(wr + 2 * 256 + c0);
            pw3 = *(const float4*)(wr + 3 * 256 + c0);
        }
        for (int cb = wvi; cb < nc; cb += 4) {
            float4 w0 = pw0, w1 = pw1, w2 = pw2, w3 = pw3;
            int cbn = cb + 4;
            if (cbn < nc) {
                const float* wr = W_enc + (size_t)cand[cbn] * C_;
                pw0 = *(const float4*)(wr + 0 * 256 + c0);
                pw1 = *(const float4*)(wr + 1 * 256 + c0);
                pw2 = *(const float4*)(wr + 2 * 256 + c0);
                pw3 = *(const float4*)(wr + 3 * 256 + c0);
            }
            int d = cand[cb];
            float a[WIN_] = {0.f, 0.f, 0.f, 0.f, 0.f, 0.f, 0.f, 0.f};
            #pragma unroll
            for (int j = 0; j < WIN_; j++) {
                float4 xq = *(const float4*)(&xs[j][0 * 256 + c0]);
                a[j] = fmaf(w0.x, xq.x, a[j]);
                a[j] = fmaf(w0.y, xq.y, a[j]);
                a[j] = fmaf(w0.z, xq.z, a[j]);
                a[j] = fmaf(w0.w, xq.w, a[j]);
            }
            #pragma unroll
            for (int j = 0; j < WIN_; j++) {
                float4 xq = *(const float4*)(&xs[j][1 * 256 + c0]);
                a[j] = fmaf(w1.x, xq.x, a[j]);
                a[j] = fmaf(w1.y, xq.y, a[j]);
                a[j] = fmaf(w1.z, xq.z, a[j]);
                a[j] = fmaf(w1.w, xq.w, a[j]);
            }
            #pragma unroll
            for (int j = 0; j < WIN_; j++) {
                float4 xq = *(const float4*)(&xs[j][2 * 256 + c0]);
                a[j] = fmaf(w2.x, xq.x, a[j]);
                a[j] = fmaf(w2.y, xq.y, a[j]);
                a[j] = fmaf(w2.z, xq.z, a[j]);
                a[j] = fmaf(w2.w, xq.w, a[j]);
            }
            #pragma unroll
            for (int j = 0; j < WIN_; j++) {
                float4 xq = *(const float4*)(&xs[j][3 * 256 + c0]);
                a[j] = fmaf(w3.x, xq.x, a[j]);
                a[j] = fmaf(w3.y, xq.y, a[j]);
                a[j] = fmaf(w3.z, xq.z, a[j]);
                a[j] = fmaf(w3.w, xq.w, a[j]);
            }
            #pragma unroll
            for (int off = 1; off < 64; off <<= 1)
                #pragma unroll
                for (int j = 0; j < WIN_; j++) a[j] += __shfl_xor(a[j], off);
            if (ln == 0) {
                float bias = benc2[d], s = 0.f;
                #pragma unroll
                for (int j = 0; j < WIN_; j++) {
                    float v = a[j] + bias;
                    s += v > 0.f ? v : 0.f;
                }
                unsigned k1 = f2key(s);
                keys[d] = k1;
                ckeys[cb] = k1;
            }
        }
    }
    __syncthreads();

    // ---- P3: finish n_hi; exact select among candidates (or fallback) ----
    for (int i = tid; i < nc; i += 256)
        if (ckeys[i] > TH_HI) atomicAdd(&sh_nhi, 1);
    __syncthreads();
    int need0 = K_ - sh_nhi;
    if (need0 > 0)
        radix_select(ckeys, nc, need0, 4, TH_HI, hist, &sh_prefix, &sh_need, tid);
    else
        radix_select(keys, D_, K_, 4, 0xFFFFFFFFu, hist, &sh_prefix, &sh_need, tid);
    unsigned kth = sh_prefix;
    int need_eq = sh_need;

    // ---- P4: bitmask + ascending index list, all in LDS ----
    int base16 = tid * 16;
    unsigned mybits = 0;
    int eqcnt = 0;
    #pragma unroll
    for (int j = 0; j < 16; ++j) {
        unsigned k = keys[base16 + j];
        if (k > kth) mybits |= (1u << j);
        else if (k == kth) eqcnt++;
    }
    int rr = block_prefix_excl(eqcnt, wsum, tid);
    #pragma unroll
    for (int j = 0; j < 16; ++j) {
        unsigned k = keys[base16 + j];
        if (k == kth) { if (rr < need_eq) mybits |= (1u << j); rr++; }
    }
    hbits[tid] = (unsigned short)mybits;     // hist dead from here on
    __syncthreads();
    if (tid < 128)
        bmask_lds[tid] = (unsigned)hbits[2 * tid] | ((unsigned)hbits[2 * tid + 1] << 16);
    int pv = (tid < 128) ? __popc((unsigned)hbits[2 * tid] | ((unsigned)hbits[2 * tid + 1] << 16)) : 0;
    int ppref = block_prefix_excl(pv, wsum, tid);
    if (tid < 128) pprefix[tid] = ppref;
    int pos = block_prefix_excl(__popc(mybits), wsum, tid);
    #pragma unroll
    for (int j = 0; j < 16; ++j) {
        if (mybits & (1u << j)) sidx[pos++] = base16 + j;
    }
    __syncthreads();   // sidx/bmask_lds/pprefix ready; keys dead -> act overlay

    // ---- P5a: MFMA recompute of the 128 selected activations (bit-exact) ----
    {
        int lane = tid & 63;
        int r = lane & 15, g = lane >> 4;
        int wvq = tid >> 6;              // wave handles tiles wvq*2, wvq*2+1
        int tsrc = (r < WIN_) ? r : 0;
        int rowA0 = sidx[(wvq * 2 + 0) * 16 + r];
        int rowA1 = sidx[(wvq * 2 + 1) * 16 + r];
        const unsigned short* pa0 = wencbf + (size_t)rowA0 * C_;
        const unsigned short* pa1 = wencbf + (size_t)rowA1 * C_;
        f32x4_t acca0 = (f32x4_t){0.f, 0.f, 0.f, 0.f};
        f32x4_t acca1 = (f32x4_t){0.f, 0.f, 0.f, 0.f};
        for (int k0 = 0; k0 < C_; k0 += 32) {
            bf16x8_t bfrag;
            #pragma unroll
            for (int j = 0; j < 8; j++)
                bfrag[j] = (short)f2bf(xs[tsrc][k0 + g * 8 + j]);
            bf16x8_t a0 = *(const bf16x8_t*)(pa0 + k0 + g * 8);
            bf16x8_t a1 = *(const bf16x8_t*)(pa1 + k0 + g * 8);
            acca0 = __builtin_amdgcn_mfma_f32_16x16x32_bf16(a0, bfrag, acca0, 0, 0, 0);
            acca1 = __builtin_amdgcn_mfma_f32_16x16x32_bf16(a1, bfrag, acca1, 0, 0, 0);
        }
        if (r < WIN_) {
            #pragma unroll
            for (int q = 0; q < 4; q++) {
                int s0 = (wvq * 2 + 0) * 16 + g * 4 + q;
                float v0 = acca0[q] + benc2[sidx[s0]];
                act[s0][r] = v0 > 0.f ? v0 : 0.f;
                int s1 = (wvq * 2 + 1) * 16 + g * 4 + q;
                float v1 = acca1[q] + benc2[sidx[s1]];
                act[s1][r] = v1 > 0.f ? v1 : 0.f;
            }
        }
    }
    __syncthreads();   // act complete

    // ---- P5b: write enc = zeros + selected values (pure write, no read) ----
    for (int jrow = 0; jrow < WIN_; jrow++) {
        float* rowp = enc + (size_t)(t0g + jrow) * D_;
        #pragma unroll
        for (int k4 = 0; k4 < 4; k4++) {
            int d4 = tid + k4 * 256;          // float4 index; d = d4*4
            int widx = d4 >> 3;
            int bit0 = (d4 & 7) * 4;
            unsigned word = bmask_lds[widx];
            unsigned nib = (word >> bit0) & 0xFu;
            float4 v = {0.f, 0.f, 0.f, 0.f};
            if (nib) {
                int rk = pprefix[widx] + __popc(word & ((1u << bit0) - 1u));
                #pragma unroll
                for (int l = 0; l < 4; l++) {
                    if (nib & (1u << l)) { ((float*)&v)[l] = act[rk][jrow]; rk++; }
                }
            }
            ((float4*)rowp)[d4] = v;
        }
    }

    // ---- P6: decode from LDS act/sidx — double-buffered 8-row prefetch ----
    {
        float accv[WIN_][4] = {};
        int c0 = tid * 4;
        ushort4 wu[8];
        #pragma unroll
        for (int u = 0; u < 8; u++)
            wu[u] = *(const ushort4*)(WdTb + (size_t)sidx[u] * C_ + c0);
        for (int i = 0; i < K_; i += 8) {
            ushort4 cur[8];
            #pragma unroll
            for (int u = 0; u < 8; u++) cur[u] = wu[u];
            if (i + 8 < K_) {
                #pragma unroll
                for (int u = 0; u < 8; u++)
                    wu[u] = *(const ushort4*)(WdTb + (size_t)sidx[i + 8 + u] * C_ + c0);
            }
            #pragma unroll
            for (int u = 0; u < 8; u++) {
                float4 wv = {bf2f(cur[u].x), bf2f(cur[u].y), bf2f(cur[u].z), bf2f(cur[u].w)};
                const float* ar = act[i + u];
                #pragma unroll
                for (int j = 0; j < WIN_; j++) {
                    float aj = ar[j];
                    accv[j][0] = fmaf(aj, wv.x, accv[j][0]);
                    accv[j][1] = fmaf(aj, wv.y, accv[j][1]);
                    accv[j][2] = fmaf(aj, wv.z, accv[j][2]);
                    accv[j][3] = fmaf(aj, wv.w, accv[j][3]);
                }
            }
        }
        float4 bd = *(const float4*)(b_dec + c0);
        #pragma unroll
        for (int j = 0; j < WIN_; j++) {
            float4 o;
            o.x = accv[j][0] + bd.x; o.y = accv[j][1] + bd.y;
            o.z = accv[j][2] + bd.z; o.w = accv[j][3] + bd.w;
            *(float4*)(recon + (size_t)(t0g + j) * C_ + c0) = o;
        }
    }
}

// ---------------------------------------------------------------------------
extern "C" void kernel_launch(void* const* d_in, const int* in_sizes, int n_in,
                              void* d_out, int out_size, void* d_ws, size_t ws_size,
                              hipStream_t stream)
{
    const float* x     = (const float*)d_in[0];
    const float* W_enc = (const float*)d_in[1];
    const float* b_enc = (const float*)d_in[2];
    const float* W_dec = (const float*)d_in[3];
    const float* b_dec = (const float*)d_in[4];

    float* out   = (float*)d_out;
    float* recon = out;                        // M_*C_ floats
    float* enc   = out + (size_t)M_ * C_;      // M_*D_ floats (written once)

    // scratch inside recon region (stream-ordered: xbf read only by GEMM,
    // wsums read only at fused-kernel block start — proven pattern)
    unsigned short* xbf   = (unsigned short*)recon;                       // 16.8 MB
    float*          wsums = (float*)((char*)recon + (size_t)M_ * C_ * 2); // 16.8 MB

    // persistent scratch in d_ws
    char* ws = (char*)d_ws;
    unsigned short* WdTb    = (unsigned short*)ws;                          // 8.4 MB (bf16)
    float*          benc2   = (float*)(ws + (size_t)D_ * C_ * 2);           // 16 KB
    unsigned short* wencbf  = (unsigned short*)((char*)benc2 + D_ * 4);     // 8.4 MB

    prep_cvt_wenc<<<D_, 256, 0, stream>>>(W_enc, b_enc, b_dec, wencbf, benc2);
    cvt_bf16<<<(M_ * C_ / 8 + 255) / 256, 256, 0, stream>>>(x, xbf, M_ * C_ / 8);
    transpose_wdec<<<dim3(D_ / 32, C_ / 32), dim3(32, 8), 0, stream>>>(W_dec, WdTb);
    mfma_gemm_ws<<<dim3(32, 64), 256, 0, stream>>>(xbf, wencbf, benc2, wsums);
    fixup_mask_decode<<<B_ * NW_, 256, 0, stream>>>(
        wsums, x, W_enc, benc2, wencbf, WdTb, b_dec, enc, recon);
}

// Round 17
// 240.187 us; speedup vs baseline: 1.1530x; 1.0228x over previous
//
#include <hip/hip_runtime.h>

#define B_   16
#define T_   512
#define C_   1024
#define D_   4096
#define K_   128
#define WIN_ 8
#define NW_  (T_ / WIN_)   // 64
#define M_   (B_ * T_)     // 8192

typedef __attribute__((ext_vector_type(8))) short bf16x8_t;
typedef __attribute__((ext_vector_type(4))) float f32x4_t;

__device__ __forceinline__ void gload16(const void* g, void* l) {
    __builtin_amdgcn_global_load_lds(
        (const __attribute__((address_space(1))) void*)g,
        (__attribute__((address_space(3))) void*)l, 16, 0, 0);
}

__device__ __forceinline__ unsigned short f2bf(float f) {
    unsigned u = __float_as_uint(f);
    unsigned r = (u + 0x7fffu + ((u >> 16) & 1u)) >> 16;
    return (unsigned short)r;
}
__device__ __forceinline__ float bf2f(unsigned short h) {
    return __uint_as_float((unsigned)h << 16);
}

__device__ __forceinline__ unsigned f2key(float f) {
    unsigned u = __float_as_uint(f);
    return (u & 0x80000000u) ? ~u : (u | 0x80000000u);
}
__device__ __forceinline__ float key2f(unsigned k) {
    unsigned u = (k & 0x80000000u) ? (k & 0x7fffffffu) : ~k;
    return __uint_as_float(u);
}

// ---------------------------------------------------------------------------
// K0 (grid-partitioned fusion of three independent prep kernels):
//   bid [0,4096):      wencbf = bf16(W_enc row d); benc2[d] = b_enc - W.b_dec
//   bid [4096,8192):   xbf = bf16(x)  (8 elems/thread)
//   bid [8192,12288):  WdTb = transpose(W_dec) in bf16
// Per-part logic byte-identical to the proven standalone kernels.
// ---------------------------------------------------------------------------
__global__ __launch_bounds__(256) void prep_all(
    const float* __restrict__ W_enc, const float* __restrict__ b_enc,
    const float* __restrict__ b_dec, unsigned short* __restrict__ wencbf,
    float* __restrict__ benc2,
    const float* __restrict__ x, unsigned short* __restrict__ xbf,
    const float* __restrict__ W_dec, unsigned short* __restrict__ WdTb)
{
    __shared__ float lds_u[32 * 33];    // union: red[256] | tile[32][33]
    int bid = blockIdx.x;
    int tid = threadIdx.x;

    if (bid < 4096) {
        // ---- part A: W_enc bf16 cvt + bias fold (1 block per dict row) ----
        int d = bid;
        float4 wv = ((const float4*)(W_enc + (size_t)d * C_))[tid];
        uint2 o;
        o.x = (unsigned)f2bf(wv.x) | ((unsigned)f2bf(wv.y) << 16);
        o.y = (unsigned)f2bf(wv.z) | ((unsigned)f2bf(wv.w) << 16);
        ((uint2*)(wencbf + (size_t)d * C_))[tid] = o;
        float4 bv = ((const float4*)b_dec)[tid];
        float s = wv.x * bv.x + wv.y * bv.y + wv.z * bv.z + wv.w * bv.w;
        float* red = lds_u;
        red[tid] = s;
        __syncthreads();
        for (int off = 128; off > 0; off >>= 1) {
            if (tid < off) red[tid] += red[tid + off];
            __syncthreads();
        }
        if (tid == 0) benc2[d] = b_enc[d] - red[0];
    } else if (bid < 8192) {
        // ---- part B: x -> bf16 (8 elems/thread) ----
        int i = (bid - 4096) * 256 + tid;
        const float4* p = (const float4*)(x + (size_t)i * 8);
        float4 a = p[0], b = p[1];
        uint4 o;
        o.x = (unsigned)f2bf(a.x) | ((unsigned)f2bf(a.y) << 16);
        o.y = (unsigned)f2bf(a.z) | ((unsigned)f2bf(a.w) << 16);
        o.z = (unsigned)f2bf(b.x) | ((unsigned)f2bf(b.y) << 16);
        o.w = (unsigned)f2bf(b.z) | ((unsigned)f2bf(b.w) << 16);
        ((uint4*)xbf)[i] = o;
    } else {
        // ---- part C: W_dec (C,D) -> WdTb (D,C) bf16, 32x32 tiles ----
        int idx = bid - 8192;
        int d0 = (idx & 127) * 32;
        int c0 = (idx >> 7) * 32;
        int tx = tid & 31, ty = tid >> 5;   // (32,8)
        float (*tile)[33] = (float(*)[33])lds_u;
        #pragma unroll
        for (int i = 0; i < 32; i += 8)
            tile[ty + i][tx] = W_dec[(size_t)(c0 + ty + i) * D_ + d0 + tx];
        __syncthreads();
        #pragma unroll
        for (int i = 0; i < 32; i += 8)
            WdTb[(size_t)(d0 + ty + i) * C_ + c0 + tx] = f2bf(tile[tx][ty + i]);
    }
}

// ---------------------------------------------------------------------------
// K3: bf16 MFMA GEMM — proven K-loop; ws-only epilogue (round-15/16 verbatim).
// ---------------------------------------------------------------------------
__global__ __launch_bounds__(256) void mfma_gemm_ws(
    const unsigned short* __restrict__ Abf,  // x bf16 (M_, C_)
    const unsigned short* __restrict__ Bbf,  // W_enc bf16 (D_, C_)
    const float* __restrict__ benc2,
    float* __restrict__ wsums)               // (B_*NW_, D_)
{
    __shared__ unsigned short lA[128 * 32];
    __shared__ unsigned short lB[128 * 32];
    __shared__ float cst[4][8][68];          // wave-private ws stage (8.7 KB)
    int tid = threadIdx.x;
    int lane = tid & 63;
    int wv = tid >> 6;
    int wm = wv >> 1, wn = wv & 1;

    int lid = blockIdx.y * gridDim.x + blockIdx.x;
    int sw = (lid & 7) * 256 + (lid >> 3);
    int bn = sw & 31, bm = sw >> 5;

    f32x4_t acc[4][4];
    #pragma unroll
    for (int i = 0; i < 4; i++)
        #pragma unroll
        for (int j = 0; j < 4; j++) acc[i][j] = (f32x4_t){0.f, 0.f, 0.f, 0.f};

    const unsigned short* Ab = Abf + (size_t)bm * 128 * C_;
    const unsigned short* Bb = Bbf + (size_t)bn * 128 * C_;

    int m_s[2], u_s[2];
    #pragma unroll
    for (int q = 0; q < 2; q++) {
        int p = q * 256 + tid;
        int m = p >> 2, v = p & 3;
        m_s[q] = m;
        u_s[q] = v ^ ((m >> 1) & 3);
    }

    int r = lane & 15, g = lane >> 4;
    for (int k0 = 0; k0 < C_; k0 += 32) {
        __syncthreads();
        #pragma unroll
        for (int q = 0; q < 2; q++) {
            gload16(Ab + (size_t)m_s[q] * C_ + k0 + u_s[q] * 8,
                    &lA[(q * 256 + wv * 64) * 8]);
            gload16(Bb + (size_t)m_s[q] * C_ + k0 + u_s[q] * 8,
                    &lB[(q * 256 + wv * 64) * 8]);
        }
        __syncthreads();
        bf16x8_t af[4], bfr[4];
        #pragma unroll
        for (int mi = 0; mi < 4; mi++) {
            int m = wm * 64 + mi * 16 + r;
            int u = g ^ ((m >> 1) & 3);
            af[mi] = *(const bf16x8_t*)&lA[m * 32 + u * 8];
        }
        #pragma unroll
        for (int ni = 0; ni < 4; ni++) {
            int d = wn * 64 + ni * 16 + r;
            int u = g ^ ((d >> 1) & 3);
            bfr[ni] = *(const bf16x8_t*)&lB[d * 32 + u * 8];
        }
        #pragma unroll
        for (int mi = 0; mi < 4; mi++)
            #pragma unroll
            for (int ni = 0; ni < 4; ni++)
                acc[mi][ni] = __builtin_amdgcn_mfma_f32_16x16x32_bf16(
                    af[mi], bfr[ni], acc[mi][ni], 0, 0, 0);
    }

    int b = bm >> 2;
    int t_blk = (bm & 3) * 128;
    int dbase = bn * 128 + wn * 64;
    int wbase = b * NW_ + (t_blk >> 3) + wm * 8;

    float bias_r[4];
    #pragma unroll
    for (int ni = 0; ni < 4; ni++) bias_r[ni] = benc2[dbase + ni * 16 + r];

    #pragma unroll
    for (int mi = 0; mi < 4; mi++) {
        #pragma unroll
        for (int ni = 0; ni < 4; ni++) {
            float s = 0.f;
            #pragma unroll
            for (int q = 0; q < 4; q++) {
                float v = acc[mi][ni][q] + bias_r[ni];
                v = v > 0.f ? v : 0.f;
                s += v;
            }
            float partner = __shfl_xor(s, 16);   // pair lane-groups (0,1),(2,3)
            float wsv = s + partner;
            if ((g & 1) == 0)
                cst[wv][mi * 2 + (g >> 1)][ni * 16 + r] = wsv;
        }
    }
    #pragma unroll
    for (int it = 0; it < 2; it++) {
        int rowq = lane >> 3;
        int c4 = (lane & 7) * 4 + it * 32;
        float4 vv = *(const float4*)&cst[wv][rowq][c4];
        *(float4*)(wsums + (size_t)(wbase + rowq) * D_ + dbase + c4) = vv;
    }
}

// ---------------------------------------------------------------------------
// Selection helpers (proven, verbatim)
// ---------------------------------------------------------------------------
__device__ __forceinline__ void find_bucket(
    const int* hist, int need, int shift, unsigned pref,
    unsigned* shp, int* shn, int tid)
{
    if (tid < 64) {
        int L = tid;
        int h0 = hist[L * 4], h1 = hist[L * 4 + 1];
        int h2 = hist[L * 4 + 2], h3 = hist[L * 4 + 3];
        int s3 = h3, s2 = h2 + s3, s1 = h1 + s2, s0 = h0 + s1;
        int T = s0, I = T;
        #pragma unroll
        for (int off = 1; off < 64; off <<= 1) {
            int t = __shfl_down(I, off);
            if (L + off < 64) I += t;
        }
        int H = I - T;   // suffix sum of buckets in higher lanes
        int S[5] = {H + s0, H + s1, H + s2, H + s3, H};
        #pragma unroll
        for (int j = 0; j < 4; j++) {
            if (S[j] >= need && S[j + 1] < need) {
                *shp = pref | ((unsigned)(L * 4 + j) << shift);
                *shn = need - S[j + 1];
            }
        }
    }
    __syncthreads();
}

__device__ __forceinline__ void radix_select(
    const unsigned* keys, int n, int need0, int npass, unsigned maxkey,
    int* hist, unsigned* shp, int* shn, int tid)
{
    if (tid == 0) { *shp = 0u; *shn = need0; }
    __syncthreads();
    for (int pass = 0; pass < npass; ++pass) {
        int shift = 24 - pass * 8;
        unsigned pref = *shp;
        int need = *shn;
        unsigned pmask = (pass == 0) ? 0u : (0xFFFFFFFFu << (shift + 8));
        hist[tid] = 0;
        __syncthreads();
        for (int i = tid; i < n; i += 256) {
            unsigned k = keys[i];
            if (k <= maxkey && (k & pmask) == pref)
                atomicAdd(&hist[(k >> shift) & 0xFF], 1);
        }
        __syncthreads();
        find_bucket(hist, need, shift, pref, shp, shn, tid);
    }
}

__device__ __forceinline__ int block_prefix_excl(int v, int* wsum, int tid)
{
    __syncthreads();                 // protect wsum reuse
    int lane = tid & 63, wv = tid >> 6;
    int x = v;
    #pragma unroll
    for (int off = 1; off < 64; off <<= 1) {
        int t = __shfl_up(x, off);
        if (lane >= off) x += t;
    }
    if (lane == 63) wsum[wv] = x;
    __syncthreads();
    int base = 0;
    #pragma unroll
    for (int w2 = 0; w2 < 3; w2++) if (w2 < wv) base += wsum[w2];
    return base + x - v;
}

// ---------------------------------------------------------------------------
// K4 (fully fused): round-16 kernel, verbatim.
// ---------------------------------------------------------------------------
#define DELTA 0.15f
#define MAXCAND 320

__global__ __launch_bounds__(256) void fixup_mask_decode(
    const float* __restrict__ wsums, const float* __restrict__ x,
    const float* __restrict__ W_enc, const float* __restrict__ benc2,
    const unsigned short* __restrict__ wencbf,
    const unsigned short* __restrict__ WdTb, const float* __restrict__ b_dec,
    float* __restrict__ enc, float* __restrict__ recon)
{
    int row = blockIdx.x;             // b*NW + w
    int b = row / NW_, w = row % NW_;
    int t0g = b * T_ + w * WIN_;
    __shared__ unsigned keys[D_];     // 16 KB (act[128][12] overlay after P4)
    __shared__ float xs[WIN_][C_];    // 32 KB (whist overlay during P1)
    __shared__ int hist[256];         // 1 KB (hbits overlay in P4)
    __shared__ int wsum[4];
    __shared__ unsigned sh_prefix;
    __shared__ int sh_need;
    __shared__ int cand[MAXCAND];     // sidx+bmask_lds overlay after P3
    __shared__ unsigned ckeys[MAXCAND];  // pprefix overlay after P3
    __shared__ int sh_ncand, sh_nhi;
    unsigned short* hbits = (unsigned short*)hist;     // P4 only
    int* whist = (int*)xs;                             // [4][256], pass-0 only
    float (*act)[12] = (float(*)[12])keys;             // [128][12], after P4
    int*      sidx      = cand;                        // [128], after P3
    unsigned* bmask_lds = (unsigned*)(cand + 128);     // [128], after P3
    int*      pprefix   = (int*)ckeys;                 // [128], after P3
    int tid = threadIdx.x;

    for (int i = tid; i < D_ / 4; i += 256) {
        float4 v = ((const float4*)(wsums + (size_t)row * D_))[i];
        keys[i * 4 + 0] = f2key(v.x);
        keys[i * 4 + 1] = f2key(v.y);
        keys[i * 4 + 2] = f2key(v.z);
        keys[i * 4 + 3] = f2key(v.w);
    }
    for (int i = tid; i < 1024; i += 256) whist[i] = 0;
    if (tid == 0) { sh_ncand = 0; sh_nhi = 0; }
    __syncthreads();

    // ---- P1 pass 0: per-wave histograms ----
    {
        int* myh = whist + (tid >> 6) * 256;
        for (int i = tid; i < D_; i += 256)
            atomicAdd(&myh[keys[i] >> 24], 1);
        __syncthreads();
        hist[tid] = whist[tid] + whist[256 + tid] + whist[512 + tid] + whist[768 + tid];
        __syncthreads();
        find_bucket(hist, K_, 24, 0u, &sh_prefix, &sh_need, tid);
    }
    // ---- P1 passes 1..2 (24-bit prefix suffices) ----
    for (int pass = 1; pass < 3; ++pass) {
        int shift = 24 - pass * 8;
        unsigned pref = sh_prefix;
        int need = sh_need;
        unsigned pmask = 0xFFFFFFFFu << (shift + 8);
        hist[tid] = 0;
        __syncthreads();
        for (int i = tid; i < D_; i += 256) {
            unsigned k = keys[i];
            if ((k & pmask) == pref)
                atomicAdd(&hist[(k >> shift) & 0xFF], 1);
        }
        __syncthreads();
        find_bucket(hist, need, shift, pref, &sh_prefix, &sh_need, tid);
    }
    float kthf = key2f(sh_prefix);
    unsigned TH_HI = f2key(kthf + DELTA);
    unsigned TH_LO = f2key(kthf - DELTA);

    // ---- load xs (whist region dead now) + collect candidates ----
    for (int i = tid; i < WIN_ * C_ / 4; i += 256)
        ((float4*)xs)[i] = ((const float4*)(x + (size_t)t0g * C_))[i];
    {
        int myhi = 0;
        for (int i = tid; i < D_; i += 256) {
            unsigned k = keys[i];
            if (k > TH_HI) myhi++;
            else if (k >= TH_LO) {
                int pos = atomicAdd(&sh_ncand, 1);
                if (pos < MAXCAND) cand[pos] = i;
            }
        }
        if (myhi) atomicAdd(&sh_nhi, myhi);
    }
    __syncthreads();
    int nc = sh_ncand < MAXCAND ? sh_ncand : MAXCAND;

    // ---- P2: exact fp32 recompute, cross-candidate load prefetch ----
    {
        int wvi = tid >> 6, ln = tid & 63;
        int c0 = ln * 4;
        float4 pw0, pw1, pw2, pw3;
        if (wvi < nc) {
            const float* wr = W_enc + (size_t)cand[wvi] * C_;
            pw0 = *(const float4*)(wr + 0 * 256 + c0);
            pw1 = *(const float4*)(wr + 1 * 256 + c0);
            pw2 = *(const float4*)(wr + 2 * 256 + c0);
            pw3 = *(const float4*)(wr + 3 * 256 + c0);
        }
        for (int cb = wvi; cb < nc; cb += 4) {
            float4 w0 = pw0, w1 = pw1, w2 = pw2, w3 = pw3;
            int cbn = cb + 4;
            if (cbn < nc) {
                const float* wr = W_enc + (size_t)cand[cbn] * C_;
                pw0 = *(const float4*)(wr + 0 * 256 + c0);
                pw1 = *(const float4*)(wr + 1 * 256 + c0);
                pw2 = *(const float4*)(wr + 2 * 256 + c0);
                pw3 = *(const float4*)(wr + 3 * 256 + c0);
            }
            int d = cand[cb];
            float a[WIN_] = {0.f, 0.f, 0.f, 0.f, 0.f, 0.f, 0.f, 0.f};
            #pragma unroll
            for (int j = 0; j < WIN_; j++) {
                float4 xq = *(const float4*)(&xs[j][0 * 256 + c0]);
                a[j] = fmaf(w0.x, xq.x, a[j]);
                a[j] = fmaf(w0.y, xq.y, a[j]);
                a[j] = fmaf(w0.z, xq.z, a[j]);
                a[j] = fmaf(w0.w, xq.w, a[j]);
            }
            #pragma unroll
            for (int j = 0; j < WIN_; j++) {
                float4 xq = *(const float4*)(&xs[j][1 * 256 + c0]);
                a[j] = fmaf(w1.x, xq.x, a[j]);
                a[j] = fmaf(w1.y, xq.y, a[j]);
                a[j] = fmaf(w1.z, xq.z, a[j]);
                a[j] = fmaf(w1.w, xq.w, a[j]);
            }
            #pragma unroll
            for (int j = 0; j < WIN_; j++) {
                float4 xq = *(const float4*)(&xs[j][2 * 256 + c0]);
                a[j] = fmaf(w2.x, xq.x, a[j]);
                a[j] = fmaf(w2.y, xq.y, a[j]);
                a[j] = fmaf(w2.z, xq.z, a[j]);
                a[j] = fmaf(w2.w, xq.w, a[j]);
            }
            #pragma unroll
            for (int j = 0; j < WIN_; j++) {
                float4 xq = *(const float4*)(&xs[j][3 * 256 + c0]);
                a[j] = fmaf(w3.x, xq.x, a[j]);
                a[j] = fmaf(w3.y, xq.y, a[j]);
                a[j] = fmaf(w3.z, xq.z, a[j]);
                a[j] = fmaf(w3.w, xq.w, a[j]);
            }
            #pragma unroll
            for (int off = 1; off < 64; off <<= 1)
                #pragma unroll
                for (int j = 0; j < WIN_; j++) a[j] += __shfl_xor(a[j], off);
            if (ln == 0) {
                float bias = benc2[d], s = 0.f;
                #pragma unroll
                for (int j = 0; j < WIN_; j++) {
                    float v = a[j] + bias;
                    s += v > 0.f ? v : 0.f;
                }
                unsigned k1 = f2key(s);
                keys[d] = k1;
                ckeys[cb] = k1;
            }
        }
    }
    __syncthreads();

    // ---- P3: finish n_hi; exact select among candidates (or fallback) ----
    for (int i = tid; i < nc; i += 256)
        if (ckeys[i] > TH_HI) atomicAdd(&sh_nhi, 1);
    __syncthreads();
    int need0 = K_ - sh_nhi;
    if (need0 > 0)
        radix_select(ckeys, nc, need0, 4, TH_HI, hist, &sh_prefix, &sh_need, tid);
    else
        radix_select(keys, D_, K_, 4, 0xFFFFFFFFu, hist, &sh_prefix, &sh_need, tid);
    unsigned kth = sh_prefix;
    int need_eq = sh_need;

    // ---- P4: bitmask + ascending index list, all in LDS ----
    int base16 = tid * 16;
    unsigned mybits = 0;
    int eqcnt = 0;
    #pragma unroll
    for (int j = 0; j < 16; ++j) {
        unsigned k = keys[base16 + j];
        if (k > kth) mybits |= (1u << j);
        else if (k == kth) eqcnt++;
    }
    int rr = block_prefix_excl(eqcnt, wsum, tid);
    #pragma unroll
    for (int j = 0; j < 16; ++j) {
        unsigned k = keys[base16 + j];
        if (k == kth) { if (rr < need_eq) mybits |= (1u << j); rr++; }
    }
    hbits[tid] = (unsigned short)mybits;     // hist dead from here on
    __syncthreads();
    if (tid < 128)
        bmask_lds[tid] = (unsigned)hbits[2 * tid] | ((unsigned)hbits[2 * tid + 1] << 16);
    int pv = (tid < 128) ? __popc((unsigned)hbits[2 * tid] | ((unsigned)hbits[2 * tid + 1] << 16)) : 0;
    int ppref = block_prefix_excl(pv, wsum, tid);
    if (tid < 128) pprefix[tid] = ppref;
    int pos = block_prefix_excl(__popc(mybits), wsum, tid);
    #pragma unroll
    for (int j = 0; j < 16; ++j) {
        if (mybits & (1u << j)) sidx[pos++] = base16 + j;
    }
    __syncthreads();   // sidx/bmask_lds/pprefix ready; keys dead -> act overlay

    // ---- P5a: MFMA recompute of the 128 selected activations (bit-exact) ----
    {
        int lane = tid & 63;
        int r = lane & 15, g = lane >> 4;
        int wvq = tid >> 6;              // wave handles tiles wvq*2, wvq*2+1
        int tsrc = (r < WIN_) ? r : 0;
        int rowA0 = sidx[(wvq * 2 + 0) * 16 + r];
        int rowA1 = sidx[(wvq * 2 + 1) * 16 + r];
        const unsigned short* pa0 = wencbf + (size_t)rowA0 * C_;
        const unsigned short* pa1 = wencbf + (size_t)rowA1 * C_;
        f32x4_t acca0 = (f32x4_t){0.f, 0.f, 0.f, 0.f};
        f32x4_t acca1 = (f32x4_t){0.f, 0.f, 0.f, 0.f};
        for (int k0 = 0; k0 < C_; k0 += 32) {
            bf16x8_t bfrag;
            #pragma unroll
            for (int j = 0; j < 8; j++)
                bfrag[j] = (short)f2bf(xs[tsrc][k0 + g * 8 + j]);
            bf16x8_t a0 = *(const bf16x8_t*)(pa0 + k0 + g * 8);
            bf16x8_t a1 = *(const bf16x8_t*)(pa1 + k0 + g * 8);
            acca0 = __builtin_amdgcn_mfma_f32_16x16x32_bf16(a0, bfrag, acca0, 0, 0, 0);
            acca1 = __builtin_amdgcn_mfma_f32_16x16x32_bf16(a1, bfrag, acca1, 0, 0, 0);
        }
        if (r < WIN_) {
            #pragma unroll
            for (int q = 0; q < 4; q++) {
                int s0 = (wvq * 2 + 0) * 16 + g * 4 + q;
                float v0 = acca0[q] + benc2[sidx[s0]];
                act[s0][r] = v0 > 0.f ? v0 : 0.f;
                int s1 = (wvq * 2 + 1) * 16 + g * 4 + q;
                float v1 = acca1[q] + benc2[sidx[s1]];
                act[s1][r] = v1 > 0.f ? v1 : 0.f;
            }
        }
    }
    __syncthreads();   // act complete

    // ---- P5b: write enc = zeros + selected values (pure write, no read) ----
    for (int jrow = 0; jrow < WIN_; jrow++) {
        float* rowp = enc + (size_t)(t0g + jrow) * D_;
        #pragma unroll
        for (int k4 = 0; k4 < 4; k4++) {
            int d4 = tid + k4 * 256;          // float4 index; d = d4*4
            int widx = d4 >> 3;
            int bit0 = (d4 & 7) * 4;
            unsigned word = bmask_lds[widx];
            unsigned nib = (word >> bit0) & 0xFu;
            float4 v = {0.f, 0.f, 0.f, 0.f};
            if (nib) {
                int rk = pprefix[widx] + __popc(word & ((1u << bit0) - 1u));
                #pragma unroll
                for (int l = 0; l < 4; l++) {
                    if (nib & (1u << l)) { ((float*)&v)[l] = act[rk][jrow]; rk++; }
                }
            }
            ((float4*)rowp)[d4] = v;
        }
    }

    // ---- P6: decode from LDS act/sidx — double-buffered 8-row prefetch ----
    {
        float accv[WIN_][4] = {};
        int c0 = tid * 4;
        ushort4 wu[8];
        #pragma unroll
        for (int u = 0; u < 8; u++)
            wu[u] = *(const ushort4*)(WdTb + (size_t)sidx[u] * C_ + c0);
        for (int i = 0; i < K_; i += 8) {
            ushort4 cur[8];
            #pragma unroll
            for (int u = 0; u < 8; u++) cur[u] = wu[u];
            if (i + 8 < K_) {
                #pragma unroll
                for (int u = 0; u < 8; u++)
                    wu[u] = *(const ushort4*)(WdTb + (size_t)sidx[i + 8 + u] * C_ + c0);
            }
            #pragma unroll
            for (int u = 0; u < 8; u++) {
                float4 wv = {bf2f(cur[u].x), bf2f(cur[u].y), bf2f(cur[u].z), bf2f(cur[u].w)};
                const float* ar = act[i + u];
                #pragma unroll
                for (int j = 0; j < WIN_; j++) {
                    float aj = ar[j];
                    accv[j][0] = fmaf(aj, wv.x, accv[j][0]);
                    accv[j][1] = fmaf(aj, wv.y, accv[j][1]);
                    accv[j][2] = fmaf(aj, wv.z, accv[j][2]);
                    accv[j][3] = fmaf(aj, wv.w, accv[j][3]);
                }
            }
        }
        float4 bd = *(const float4*)(b_dec + c0);
        #pragma unroll
        for (int j = 0; j < WIN_; j++) {
            float4 o;
            o.x = accv[j][0] + bd.x; o.y = accv[j][1] + bd.y;
            o.z = accv[j][2] + bd.z; o.w = accv[j][3] + bd.w;
            *(float4*)(recon + (size_t)(t0g + j) * C_ + c0) = o;
        }
    }
}

// ---------------------------------------------------------------------------
extern "C" void kernel_launch(void* const* d_in, const int* in_sizes, int n_in,
                              void* d_out, int out_size, void* d_ws, size_t ws_size,
                              hipStream_t stream)
{
    const float* x     = (const float*)d_in[0];
    const float* W_enc = (const float*)d_in[1];
    const float* b_enc = (const float*)d_in[2];
    const float* W_dec = (const float*)d_in[3];
    const float* b_dec = (const float*)d_in[4];

    float* out   = (float*)d_out;
    float* recon = out;                        // M_*C_ floats
    float* enc   = out + (size_t)M_ * C_;      // M_*D_ floats (written once)

    // scratch inside recon region (stream-ordered: xbf read only by GEMM,
    // wsums read only at fused-kernel block start — proven pattern)
    unsigned short* xbf   = (unsigned short*)recon;                       // 16.8 MB
    float*          wsums = (float*)((char*)recon + (size_t)M_ * C_ * 2); // 16.8 MB

    // persistent scratch in d_ws
    char* ws = (char*)d_ws;
    unsigned short* WdTb    = (unsigned short*)ws;                          // 8.4 MB (bf16)
    float*          benc2   = (float*)(ws + (size_t)D_ * C_ * 2);           // 16 KB
    unsigned short* wencbf  = (unsigned short*)((char*)benc2 + D_ * 4);     // 8.4 MB

    prep_all<<<12288, 256, 0, stream>>>(W_enc, b_enc, b_dec, wencbf, benc2,
                                        x, xbf, W_dec, WdTb);
    mfma_gemm_ws<<<dim3(32, 64), 256, 0, stream>>>(xbf, wencbf, benc2, wsums);
    fixup_mask_decode<<<B_ * NW_, 256, 0, stream>>>(
        wsums, x, W_enc, benc2, wencbf, WdTb, b_dec, enc, recon);
}